// Round 2
// baseline (7950.790 us; speedup 1.0000x reference)
//
#include <hip/hip_runtime.h>
#include <hip/hip_bf16.h>
#include <cstddef>

typedef __bf16 bf16;
typedef __attribute__((ext_vector_type(8))) __bf16 bf16x8;
typedef __attribute__((ext_vector_type(4))) float f32x4;

constexpr int VOC = 32000;
constexpr int DIM = 512;
constexpr int NH  = 8;
constexpr int HSZ = 64;
constexpr int SEQ = 2048;
constexpr int NB  = 2;
constexpr int NL  = 4;
constexpr int NTOK = NB * SEQ;  // 4096 rows

// ---------------------------------------------------------------- embedding
__global__ __launch_bounds__(256) void embed_kernel(
    const int* __restrict__ idx, const float* __restrict__ tok,
    const float* __restrict__ pos, float* __restrict__ x) {
  int i = blockIdx.x * 256 + threadIdx.x;   // over NTOK*DIM
  int row = i >> 9;                         // / DIM
  int d = i & (DIM - 1);
  int t = row & (SEQ - 1);
  int tk = idx[row];
  x[i] = tok[(size_t)tk * DIM + d] + pos[(size_t)t * DIM + d];
}

// ---------------------------------------------------------------- layernorm
__global__ __launch_bounds__(256) void ln_kernel(
    const float* __restrict__ x, const float* __restrict__ g,
    const float* __restrict__ b, float* __restrict__ out) {
  __shared__ float s1[256], s2[256];
  int row = blockIdx.x;
  int tid = threadIdx.x;
  const float* xr = x + (size_t)row * DIM;
  float a0 = xr[tid], a1 = xr[tid + 256];
  s1[tid] = a0 + a1;
  s2[tid] = a0 * a0 + a1 * a1;
  __syncthreads();
  for (int off = 128; off > 0; off >>= 1) {
    if (tid < off) { s1[tid] += s1[tid + off]; s2[tid] += s2[tid + off]; }
    __syncthreads();
  }
  float mu = s1[0] * (1.0f / DIM);
  float var = s2[0] * (1.0f / DIM) - mu * mu;
  float rs = rsqrtf(var + 1e-5f);
  out[(size_t)row * DIM + tid] = (a0 - mu) * rs * g[tid] + b[tid];
  out[(size_t)row * DIM + tid + 256] =
      (a1 - mu) * rs * g[tid + 256] + b[tid + 256];
}

// ---------------------------------------------------------------- GEMM
// C[M,N] = A[M,K](f32->bf16) @ W[K,N](f32->bf16) [+bias] [relu] [+res] -> f32
// tile 64x64, BK=32, 4 waves; wave w owns rows w*16..w*16+15, 4 n-subtiles.
template <bool RELU, bool RES>
__global__ __launch_bounds__(256) void gemm_kernel(
    const float* __restrict__ A, const float* __restrict__ W,
    const float* __restrict__ bias, const float* __restrict__ res,
    float* __restrict__ out, int K, int N) {
  __shared__ bf16 As[64][32];   // [m][k]
  __shared__ bf16 Bs[64][32];   // [n][k]  (transposed stage)
  int tid = threadIdx.x;
  int wave = tid >> 6, lane = tid & 63;
  int m0 = blockIdx.y * 64, n0 = blockIdx.x * 64;
  f32x4 acc[4] = {};
  int ar = tid >> 2, ac = (tid & 3) * 8;      // A stage: 8 contiguous k
  int bk = tid >> 3, bc = (tid & 7) * 8;      // B stage: 8 contiguous n
  int mrow = wave * 16 + (lane & 15);
  int kcol = (lane >> 4) * 8;

  for (int k0 = 0; k0 < K; k0 += 32) {
    const float* asrc = A + (size_t)(m0 + ar) * K + k0 + ac;
    float4 f0 = *(const float4*)asrc;
    float4 f1 = *(const float4*)(asrc + 4);
    bf16x8 av;
    av[0] = (bf16)f0.x; av[1] = (bf16)f0.y; av[2] = (bf16)f0.z; av[3] = (bf16)f0.w;
    av[4] = (bf16)f1.x; av[5] = (bf16)f1.y; av[6] = (bf16)f1.z; av[7] = (bf16)f1.w;
    const float* wsrc = W + (size_t)(k0 + bk) * N + n0 + bc;
    float4 w0 = *(const float4*)wsrc;
    float4 w1 = *(const float4*)(wsrc + 4);
    __syncthreads();                 // protect previous iteration's reads
    *(bf16x8*)&As[ar][ac] = av;
    Bs[bc + 0][bk] = (bf16)w0.x; Bs[bc + 1][bk] = (bf16)w0.y;
    Bs[bc + 2][bk] = (bf16)w0.z; Bs[bc + 3][bk] = (bf16)w0.w;
    Bs[bc + 4][bk] = (bf16)w1.x; Bs[bc + 5][bk] = (bf16)w1.y;
    Bs[bc + 6][bk] = (bf16)w1.z; Bs[bc + 7][bk] = (bf16)w1.w;
    __syncthreads();
    bf16x8 af = *(const bf16x8*)&As[mrow][kcol];
#pragma unroll
    for (int nt = 0; nt < 4; ++nt) {
      bf16x8 bfr = *(const bf16x8*)&Bs[nt * 16 + (lane & 15)][kcol];
      acc[nt] = __builtin_amdgcn_mfma_f32_16x16x32_bf16(af, bfr, acc[nt], 0, 0, 0);
    }
  }

  // epilogue: D[m][n]: col = lane&15, row = (lane>>4)*4 + i   (HW-verified)
  int rb = wave * 16 + (lane >> 4) * 4;
  int cb = lane & 15;
#pragma unroll
  for (int nt = 0; nt < 4; ++nt) {
    int n = n0 + nt * 16 + cb;
    float bval = bias ? bias[n] : 0.0f;
#pragma unroll
    for (int i = 0; i < 4; ++i) {
      int m = m0 + rb + i;
      float val = acc[nt][i] + bval;
      if (RELU) val = fmaxf(val, 0.0f);
      if (RES) val += res[(size_t)m * N + n];
      out[(size_t)m * N + n] = val;
    }
  }
}

// ---------------------------------------------------------------- attention
// one block per (t, h, b): causal softmax(q_t . k_j * scale) @ v
__global__ __launch_bounds__(256) void attn_kernel(
    const float* __restrict__ q, const float* __restrict__ k,
    const float* __restrict__ v, float* __restrict__ att) {
  __shared__ float qs[HSZ];
  __shared__ float p[SEQ];
  __shared__ float red[256];
  int t = blockIdx.x, h = blockIdx.y, b = blockIdx.z;
  int tid = threadIdx.x;
  const size_t base = ((size_t)b * SEQ) * DIM + (size_t)h * HSZ;
  if (tid < HSZ) qs[tid] = q[base + (size_t)t * DIM + tid];
  __syncthreads();
  float lmax = -1e30f;
  for (int j = tid; j <= t; j += 256) {
    const float* krow = k + base + (size_t)j * DIM;
    float s = 0.f;
#pragma unroll
    for (int d4 = 0; d4 < HSZ / 4; ++d4) {
      float4 kv = ((const float4*)krow)[d4];
      float4 qv = ((const float4*)qs)[d4];
      s += kv.x * qv.x + kv.y * qv.y + kv.z * qv.z + kv.w * qv.w;
    }
    s *= 0.125f;   // HS^-0.5
    p[j] = s;
    lmax = fmaxf(lmax, s);
  }
  red[tid] = lmax; __syncthreads();
  for (int off = 128; off > 0; off >>= 1) {
    if (tid < off) red[tid] = fmaxf(red[tid], red[tid + off]);
    __syncthreads();
  }
  float mx = red[0];
  __syncthreads();
  float lsum = 0.f;
  for (int j = tid; j <= t; j += 256) {
    float e = expf(p[j] - mx);
    p[j] = e;
    lsum += e;
  }
  red[tid] = lsum; __syncthreads();
  for (int off = 128; off > 0; off >>= 1) {
    if (tid < off) red[tid] += red[tid + off];
    __syncthreads();
  }
  float inv = 1.0f / red[0];
  __syncthreads();
  int d = tid & 63, g = tid >> 6;
  float acc = 0.f;
  for (int j = g; j <= t; j += 4)
    acc += p[j] * v[base + (size_t)j * DIM + d];
  red[tid] = acc; __syncthreads();
  if (tid < 64) {
    float r = red[tid] + red[tid + 64] + red[tid + 128] + red[tid + 192];
    att[base + (size_t)t * DIM + tid] = r * inv;
  }
}

// ---------------------------------------------------------------- launcher
extern "C" void kernel_launch(void* const* d_in, const int* in_sizes, int n_in,
                              void* d_out, int out_size, void* d_ws, size_t ws_size,
                              hipStream_t stream) {
  const int*   idx    = (const int*)d_in[0];
  const float* tok    = (const float*)d_in[1];
  const float* pos    = (const float*)d_in[2];
  const float* ln1_g  = (const float*)d_in[3];
  const float* ln1_b  = (const float*)d_in[4];
  const float* wq     = (const float*)d_in[5];
  const float* wk     = (const float*)d_in[6];
  const float* wv     = (const float*)d_in[7];
  const float* wo     = (const float*)d_in[8];
  const float* bo     = (const float*)d_in[9];
  const float* ln2_g  = (const float*)d_in[10];
  const float* ln2_b  = (const float*)d_in[11];
  const float* w1     = (const float*)d_in[12];
  const float* b1     = (const float*)d_in[13];
  const float* w2     = (const float*)d_in[14];
  const float* b2     = (const float*)d_in[15];
  const float* lnf_g  = (const float*)d_in[16];
  const float* lnf_b  = (const float*)d_in[17];
  const float* head_w = (const float*)d_in[18];
  const float* head_b = (const float*)d_in[19];

  float* ws = (float*)d_ws;
  float* x   = ws;                  // [4096,512] f32
  float* h   = ws + 2097152;        // [4096,512]
  float* q   = ws + 4194304;        // [4096,512]
  float* k   = ws + 6291456;        // [4096,512]
  float* v   = ws + 8388608;        // [4096,512]
  float* att = ws + 10485760;       // [4096,512]
  float* ffn = ws + 12582912;       // [4096,2048]   (total 80 MB)

  embed_kernel<<<NTOK * DIM / 256, 256, 0, stream>>>(idx, tok, pos, x);

  dim3 gD(DIM / 64, NTOK / 64);        // (8, 64)
  dim3 gF(4 * DIM / 64, NTOK / 64);    // (32, 64)
  dim3 gV(VOC / 64, NTOK / 64);        // (500, 64)
  dim3 gA(SEQ, NH, NB);

  for (int l = 0; l < NL; ++l) {
    ln_kernel<<<NTOK, 256, 0, stream>>>(x, ln1_g + l * DIM, ln1_b + l * DIM, h);
    gemm_kernel<false, false><<<gD, 256, 0, stream>>>(
        h, wq + (size_t)l * DIM * DIM, nullptr, nullptr, q, DIM, DIM);
    gemm_kernel<false, false><<<gD, 256, 0, stream>>>(
        h, wk + (size_t)l * DIM * DIM, nullptr, nullptr, k, DIM, DIM);
    gemm_kernel<false, false><<<gD, 256, 0, stream>>>(
        h, wv + (size_t)l * DIM * DIM, nullptr, nullptr, v, DIM, DIM);
    attn_kernel<<<gA, 256, 0, stream>>>(q, k, v, att);
    gemm_kernel<false, true><<<gD, 256, 0, stream>>>(
        att, wo + (size_t)l * DIM * DIM, bo + l * DIM, x, x, DIM, DIM);
    ln_kernel<<<NTOK, 256, 0, stream>>>(x, ln2_g + l * DIM, ln2_b + l * DIM, h);
    gemm_kernel<true, false><<<gF, 256, 0, stream>>>(
        h, w1 + (size_t)l * DIM * 4 * DIM, b1 + (size_t)l * 4 * DIM, nullptr,
        ffn, DIM, 4 * DIM);
    gemm_kernel<false, true><<<gD, 256, 0, stream>>>(
        ffn, w2 + (size_t)l * 4 * DIM * DIM, b2 + l * DIM, x, x, 4 * DIM, DIM);
  }

  ln_kernel<<<NTOK, 256, 0, stream>>>(x, lnf_g, lnf_b, h);
  gemm_kernel<false, false><<<gV, 256, 0, stream>>>(
      h, head_w, head_b, nullptr, (float*)d_out, DIM, VOC);
}

// Round 3
// 1989.466 us; speedup vs baseline: 3.9964x; 3.9964x over previous
//
#include <hip/hip_runtime.h>
#include <hip/hip_bf16.h>
#include <cstddef>

typedef __bf16 bf16;
typedef __attribute__((ext_vector_type(8))) __bf16 bf16x8;
typedef __attribute__((ext_vector_type(4))) float f32x4;

constexpr int VOC = 32000;
constexpr int DIM = 512;
constexpr int NH  = 8;
constexpr int HSZ = 64;
constexpr int SEQ = 2048;
constexpr int NB  = 2;
constexpr int NL  = 4;
constexpr int NTOK = NB * SEQ;  // 4096 rows

// ---------------------------------------------------------------- embedding
__global__ __launch_bounds__(256) void embed_kernel(
    const int* __restrict__ idx, const float* __restrict__ tok,
    const float* __restrict__ pos, float* __restrict__ x) {
  int i = blockIdx.x * 256 + threadIdx.x;   // over NTOK*DIM
  int row = i >> 9;                         // / DIM
  int d = i & (DIM - 1);
  int t = row & (SEQ - 1);
  int tk = idx[row];
  x[i] = tok[(size_t)tk * DIM + d] + pos[(size_t)t * DIM + d];
}

// ---------------------------------------------------------------- layernorm
__global__ __launch_bounds__(256) void ln_kernel(
    const float* __restrict__ x, const float* __restrict__ g,
    const float* __restrict__ b, float* __restrict__ out) {
  __shared__ float s1[256], s2[256];
  int row = blockIdx.x;
  int tid = threadIdx.x;
  const float* xr = x + (size_t)row * DIM;
  float a0 = xr[tid], a1 = xr[tid + 256];
  s1[tid] = a0 + a1;
  s2[tid] = a0 * a0 + a1 * a1;
  __syncthreads();
  for (int off = 128; off > 0; off >>= 1) {
    if (tid < off) { s1[tid] += s1[tid + off]; s2[tid] += s2[tid + off]; }
    __syncthreads();
  }
  float mu = s1[0] * (1.0f / DIM);
  float var = s2[0] * (1.0f / DIM) - mu * mu;
  float rs = rsqrtf(var + 1e-5f);
  out[(size_t)row * DIM + tid] = (a0 - mu) * rs * g[tid] + b[tid];
  out[(size_t)row * DIM + tid + 256] =
      (a1 - mu) * rs * g[tid + 256] + b[tid + 256];
}

// ---------------------------------------------------------------- GEMM
// C[M,N] = A[M,K](f32->bf16) @ W[K,N](f32->bf16) [+bias] [relu] [+res] -> f32
template <bool RELU, bool RES>
__global__ __launch_bounds__(256) void gemm_kernel(
    const float* __restrict__ A, const float* __restrict__ W,
    const float* __restrict__ bias, const float* __restrict__ res,
    float* __restrict__ out, int K, int N) {
  __shared__ bf16 As[64][32];   // [m][k]
  __shared__ bf16 Bs[64][32];   // [n][k]  (transposed stage)
  int tid = threadIdx.x;
  int wave = tid >> 6, lane = tid & 63;
  int m0 = blockIdx.y * 64, n0 = blockIdx.x * 64;
  f32x4 acc[4] = {};
  int ar = tid >> 2, ac = (tid & 3) * 8;      // A stage: 8 contiguous k
  int bk = tid >> 3, bc = (tid & 7) * 8;      // B stage: 8 contiguous n
  int mrow = wave * 16 + (lane & 15);
  int kcol = (lane >> 4) * 8;

  for (int k0 = 0; k0 < K; k0 += 32) {
    const float* asrc = A + (size_t)(m0 + ar) * K + k0 + ac;
    float4 f0 = *(const float4*)asrc;
    float4 f1 = *(const float4*)(asrc + 4);
    bf16x8 av;
    av[0] = (bf16)f0.x; av[1] = (bf16)f0.y; av[2] = (bf16)f0.z; av[3] = (bf16)f0.w;
    av[4] = (bf16)f1.x; av[5] = (bf16)f1.y; av[6] = (bf16)f1.z; av[7] = (bf16)f1.w;
    const float* wsrc = W + (size_t)(k0 + bk) * N + n0 + bc;
    float4 w0 = *(const float4*)wsrc;
    float4 w1 = *(const float4*)(wsrc + 4);
    __syncthreads();                 // protect previous iteration's reads
    *(bf16x8*)&As[ar][ac] = av;
    Bs[bc + 0][bk] = (bf16)w0.x; Bs[bc + 1][bk] = (bf16)w0.y;
    Bs[bc + 2][bk] = (bf16)w0.z; Bs[bc + 3][bk] = (bf16)w0.w;
    Bs[bc + 4][bk] = (bf16)w1.x; Bs[bc + 5][bk] = (bf16)w1.y;
    Bs[bc + 6][bk] = (bf16)w1.z; Bs[bc + 7][bk] = (bf16)w1.w;
    __syncthreads();
    bf16x8 af = *(const bf16x8*)&As[mrow][kcol];
#pragma unroll
    for (int nt = 0; nt < 4; ++nt) {
      bf16x8 bfr = *(const bf16x8*)&Bs[nt * 16 + (lane & 15)][kcol];
      acc[nt] = __builtin_amdgcn_mfma_f32_16x16x32_bf16(af, bfr, acc[nt], 0, 0, 0);
    }
  }

  // epilogue: D[m][n]: col = lane&15, row = (lane>>4)*4 + i
  int rb = wave * 16 + (lane >> 4) * 4;
  int cb = lane & 15;
#pragma unroll
  for (int nt = 0; nt < 4; ++nt) {
    int n = n0 + nt * 16 + cb;
    float bval = bias ? bias[n] : 0.0f;
#pragma unroll
    for (int i = 0; i < 4; ++i) {
      int m = m0 + rb + i;
      float val = acc[nt][i] + bval;
      if (RELU) val = fmaxf(val, 0.0f);
      if (RES) val += res[(size_t)m * N + n];
      out[(size_t)m * N + n] = val;
    }
  }
}

// ---------------------------------------------------------------- flash attn
// Block: 4 waves, 64 q-rows of one (b,h). Wave w: q rows qt0+w*16..+15.
// KV tiles of 32; K in LDS [32][72] bf16, V transposed [64][40] bf16.
// S=QK^T (4 mfma), in-register online softmax, P via wave-private LDS, PV (4 mfma).
__global__ __launch_bounds__(256) void fattn_kernel(
    const float* __restrict__ q, const float* __restrict__ k,
    const float* __restrict__ v, float* __restrict__ att) {
  __shared__ bf16 Ks[32][72];
  __shared__ bf16 Vt[64][40];
  __shared__ bf16 Pl[4][16][40];
  int tid = threadIdx.x;
  int wave = tid >> 6, lane = tid & 63;
  int lr = lane & 15, lg = lane >> 4;
  int qt0 = blockIdx.x * 64;
  int h = blockIdx.y, b = blockIdx.z;
  const size_t base = ((size_t)b * SEQ) * DIM + (size_t)h * HSZ;

  // Q fragments (A layout: row = lane&15, k-octet = (lane>>4)*8)
  bf16x8 aq[2];
  {
    const float* qr = q + base + (size_t)(qt0 + wave * 16 + lr) * DIM + lg * 8;
#pragma unroll
    for (int c = 0; c < 2; ++c) {
      float4 f0 = *(const float4*)(qr + c * 32);
      float4 f1 = *(const float4*)(qr + c * 32 + 4);
      aq[c][0] = (bf16)f0.x; aq[c][1] = (bf16)f0.y;
      aq[c][2] = (bf16)f0.z; aq[c][3] = (bf16)f0.w;
      aq[c][4] = (bf16)f1.x; aq[c][5] = (bf16)f1.y;
      aq[c][6] = (bf16)f1.z; aq[c][7] = (bf16)f1.w;
    }
  }

  f32x4 accO[4] = {};
  float m_r[4] = {-1e30f, -1e30f, -1e30f, -1e30f};
  float l_r[4] = {0.f, 0.f, 0.f, 0.f};

  int srow = tid >> 3, sd0 = (tid & 7) * 8;
  int ntile = qt0 / 32 + 2;
  for (int ti = 0; ti < ntile; ++ti) {
    int kv0 = ti * 32;
    const float* ksrc = k + base + (size_t)(kv0 + srow) * DIM + sd0;
    float4 k0 = *(const float4*)ksrc, k1 = *(const float4*)(ksrc + 4);
    const float* vsrc = v + base + (size_t)(kv0 + srow) * DIM + sd0;
    float4 v0 = *(const float4*)vsrc, v1 = *(const float4*)(vsrc + 4);
    __syncthreads();   // prior tile's LDS reads done
    bf16x8 kb;
    kb[0] = (bf16)k0.x; kb[1] = (bf16)k0.y; kb[2] = (bf16)k0.z; kb[3] = (bf16)k0.w;
    kb[4] = (bf16)k1.x; kb[5] = (bf16)k1.y; kb[6] = (bf16)k1.z; kb[7] = (bf16)k1.w;
    *(bf16x8*)&Ks[srow][sd0] = kb;
    Vt[sd0 + 0][srow] = (bf16)v0.x; Vt[sd0 + 1][srow] = (bf16)v0.y;
    Vt[sd0 + 2][srow] = (bf16)v0.z; Vt[sd0 + 3][srow] = (bf16)v0.w;
    Vt[sd0 + 4][srow] = (bf16)v1.x; Vt[sd0 + 5][srow] = (bf16)v1.y;
    Vt[sd0 + 6][srow] = (bf16)v1.z; Vt[sd0 + 7][srow] = (bf16)v1.w;
    __syncthreads();   // tile staged

    // S = Q K^T : per wave 16x32 scores
    f32x4 sc[2];
#pragma unroll
    for (int s = 0; s < 2; ++s) {
      bf16x8 b0 = *(const bf16x8*)&Ks[s * 16 + lr][lg * 8];
      bf16x8 b1 = *(const bf16x8*)&Ks[s * 16 + lr][32 + lg * 8];
      f32x4 z = {};
      z = __builtin_amdgcn_mfma_f32_16x16x32_bf16(aq[0], b0, z, 0, 0, 0);
      sc[s] = __builtin_amdgcn_mfma_f32_16x16x32_bf16(aq[1], b1, z, 0, 0, 0);
    }

    // mask + online softmax (C layout: row = lg*4+i, col = lr)
#pragma unroll
    for (int i = 0; i < 4; ++i) {
      int qrow = qt0 + wave * 16 + lg * 4 + i;
#pragma unroll
      for (int s = 0; s < 2; ++s) {
        int kvc = kv0 + s * 16 + lr;
        float val = sc[s][i] * 0.125f;
        sc[s][i] = (kvc <= qrow) ? val : -1e30f;
      }
      float t = fmaxf(sc[0][i], sc[1][i]);
      t = fmaxf(t, __shfl_xor(t, 1, 64));
      t = fmaxf(t, __shfl_xor(t, 2, 64));
      t = fmaxf(t, __shfl_xor(t, 4, 64));
      t = fmaxf(t, __shfl_xor(t, 8, 64));
      float mn = fmaxf(m_r[i], t);
      float alpha = __expf(m_r[i] - mn);
      m_r[i] = mn;
      float p0 = __expf(sc[0][i] - mn);
      float p1 = __expf(sc[1][i] - mn);
      sc[0][i] = p0; sc[1][i] = p1;
      float rs = p0 + p1;
      rs += __shfl_xor(rs, 1, 64);
      rs += __shfl_xor(rs, 2, 64);
      rs += __shfl_xor(rs, 4, 64);
      rs += __shfl_xor(rs, 8, 64);
      l_r[i] = l_r[i] * alpha + rs;
#pragma unroll
      for (int ds = 0; ds < 4; ++ds) accO[ds][i] *= alpha;
    }

    // P: C layout -> LDS (wave-private) -> A fragment
#pragma unroll
    for (int i = 0; i < 4; ++i) {
      Pl[wave][lg * 4 + i][lr]      = (bf16)sc[0][i];
      Pl[wave][lg * 4 + i][16 + lr] = (bf16)sc[1][i];
    }
    bf16x8 pa = *(const bf16x8*)&Pl[wave][lr][lg * 8];

#pragma unroll
    for (int ds = 0; ds < 4; ++ds) {
      bf16x8 bv = *(const bf16x8*)&Vt[ds * 16 + lr][lg * 8];
      accO[ds] = __builtin_amdgcn_mfma_f32_16x16x32_bf16(pa, bv, accO[ds], 0, 0, 0);
    }
  }

  // epilogue: O / l
#pragma unroll
  for (int i = 0; i < 4; ++i) {
    float inv = 1.0f / l_r[i];
    size_t orow = base + (size_t)(qt0 + wave * 16 + lg * 4 + i) * DIM;
#pragma unroll
    for (int ds = 0; ds < 4; ++ds)
      att[orow + ds * 16 + lr] = accO[ds][i] * inv;
  }
}

// ---------------------------------------------------------------- launcher
extern "C" void kernel_launch(void* const* d_in, const int* in_sizes, int n_in,
                              void* d_out, int out_size, void* d_ws, size_t ws_size,
                              hipStream_t stream) {
  const int*   idx    = (const int*)d_in[0];
  const float* tok    = (const float*)d_in[1];
  const float* pos    = (const float*)d_in[2];
  const float* ln1_g  = (const float*)d_in[3];
  const float* ln1_b  = (const float*)d_in[4];
  const float* wq     = (const float*)d_in[5];
  const float* wk     = (const float*)d_in[6];
  const float* wv     = (const float*)d_in[7];
  const float* wo     = (const float*)d_in[8];
  const float* bo     = (const float*)d_in[9];
  const float* ln2_g  = (const float*)d_in[10];
  const float* ln2_b  = (const float*)d_in[11];
  const float* w1     = (const float*)d_in[12];
  const float* b1     = (const float*)d_in[13];
  const float* w2     = (const float*)d_in[14];
  const float* b2     = (const float*)d_in[15];
  const float* lnf_g  = (const float*)d_in[16];
  const float* lnf_b  = (const float*)d_in[17];
  const float* head_w = (const float*)d_in[18];
  const float* head_b = (const float*)d_in[19];

  float* ws = (float*)d_ws;
  float* x   = ws;                  // [4096,512] f32
  float* h   = ws + 2097152;        // [4096,512]
  float* q   = ws + 4194304;        // [4096,512]
  float* k   = ws + 6291456;        // [4096,512]
  float* v   = ws + 8388608;        // [4096,512]
  float* att = ws + 10485760;       // [4096,512]
  float* ffn = ws + 12582912;       // [4096,2048]   (total 80 MB)

  embed_kernel<<<NTOK * DIM / 256, 256, 0, stream>>>(idx, tok, pos, x);

  dim3 gD(DIM / 64, NTOK / 64);        // (8, 64)
  dim3 gF(4 * DIM / 64, NTOK / 64);    // (32, 64)
  dim3 gV(VOC / 64, NTOK / 64);        // (500, 64)
  dim3 gA(SEQ / 64, NH, NB);           // (32, 8, 2)

  for (int l = 0; l < NL; ++l) {
    ln_kernel<<<NTOK, 256, 0, stream>>>(x, ln1_g + l * DIM, ln1_b + l * DIM, h);
    gemm_kernel<false, false><<<gD, 256, 0, stream>>>(
        h, wq + (size_t)l * DIM * DIM, nullptr, nullptr, q, DIM, DIM);
    gemm_kernel<false, false><<<gD, 256, 0, stream>>>(
        h, wk + (size_t)l * DIM * DIM, nullptr, nullptr, k, DIM, DIM);
    gemm_kernel<false, false><<<gD, 256, 0, stream>>>(
        h, wv + (size_t)l * DIM * DIM, nullptr, nullptr, v, DIM, DIM);
    fattn_kernel<<<gA, 256, 0, stream>>>(q, k, v, att);
    gemm_kernel<false, true><<<gD, 256, 0, stream>>>(
        att, wo + (size_t)l * DIM * DIM, bo + l * DIM, x, x, DIM, DIM);
    ln_kernel<<<NTOK, 256, 0, stream>>>(x, ln2_g + l * DIM, ln2_b + l * DIM, h);
    gemm_kernel<true, false><<<gF, 256, 0, stream>>>(
        h, w1 + (size_t)l * DIM * 4 * DIM, b1 + (size_t)l * 4 * DIM, nullptr,
        ffn, DIM, 4 * DIM);
    gemm_kernel<false, true><<<gD, 256, 0, stream>>>(
        ffn, w2 + (size_t)l * 4 * DIM * DIM, b2 + l * DIM, x, x, 4 * DIM, DIM);
  }

  ln_kernel<<<NTOK, 256, 0, stream>>>(x, lnf_g, lnf_b, h);
  gemm_kernel<false, false><<<gV, 256, 0, stream>>>(
      h, head_w, head_b, nullptr, (float*)d_out, DIM, VOC);
}

// Round 4
// 1198.011 us; speedup vs baseline: 6.6367x; 1.6606x over previous
//
#include <hip/hip_runtime.h>
#include <hip/hip_bf16.h>
#include <cstddef>

typedef __bf16 bf16;
typedef __attribute__((ext_vector_type(8))) __bf16 bf16x8;
typedef __attribute__((ext_vector_type(4))) float f32x4;

constexpr int VOC = 32000;
constexpr int DIM = 512;
constexpr int NH  = 8;
constexpr int HSZ = 64;
constexpr int SEQ = 2048;
constexpr int NB  = 2;
constexpr int NL  = 4;
constexpr int NTOK = NB * SEQ;  // 4096 rows
constexpr int QS  = 3 * DIM;    // packed qkv row stride

// ---------------------------------------------------------------- embedding
__global__ __launch_bounds__(256) void embed_kernel(
    const int* __restrict__ idx, const float* __restrict__ tok,
    const float* __restrict__ pos, float* __restrict__ x) {
  int i = blockIdx.x * 256 + threadIdx.x;   // over NTOK*DIM
  int row = i >> 9;                         // / DIM
  int d = i & (DIM - 1);
  int t = row & (SEQ - 1);
  int tk = idx[row];
  x[i] = tok[(size_t)tk * DIM + d] + pos[(size_t)t * DIM + d];
}

// ------------------------------------------------- weight transpose + cast
// w [K][N] f32  ->  wt [N][K] bf16   (32x32 tiles, 256 threads)
__global__ __launch_bounds__(256) void wt_kernel(
    const float* __restrict__ w, bf16* __restrict__ wt, int K, int N) {
  __shared__ float t[32][33];
  int n0 = blockIdx.x * 32, k0 = blockIdx.y * 32;
  int tx = threadIdx.x & 31, ty = threadIdx.x >> 5;
#pragma unroll
  for (int r = 0; r < 4; ++r)
    t[ty + r * 8][tx] = w[(size_t)(k0 + ty + r * 8) * N + n0 + tx];
  __syncthreads();
#pragma unroll
  for (int r = 0; r < 4; ++r)
    wt[(size_t)(n0 + ty + r * 8) * K + k0 + tx] = (bf16)t[tx][ty + r * 8];
}

// ---------------------------------------------------------------- layernorm
__global__ __launch_bounds__(256) void ln_kernel(
    const float* __restrict__ x, const float* __restrict__ g,
    const float* __restrict__ b, bf16* __restrict__ out) {
  __shared__ float s1[256], s2[256];
  int row = blockIdx.x;
  int tid = threadIdx.x;
  const float* xr = x + (size_t)row * DIM;
  float a0 = xr[tid], a1 = xr[tid + 256];
  s1[tid] = a0 + a1;
  s2[tid] = a0 * a0 + a1 * a1;
  __syncthreads();
  for (int off = 128; off > 0; off >>= 1) {
    if (tid < off) { s1[tid] += s1[tid + off]; s2[tid] += s2[tid + off]; }
    __syncthreads();
  }
  float mu = s1[0] * (1.0f / DIM);
  float var = s2[0] * (1.0f / DIM) - mu * mu;
  float rs = rsqrtf(var + 1e-5f);
  out[(size_t)row * DIM + tid] = (bf16)((a0 - mu) * rs * g[tid] + b[tid]);
  out[(size_t)row * DIM + tid + 256] =
      (bf16)((a1 - mu) * rs * g[tid + 256] + b[tid + 256]);
}

// ---------------------------------------------------------------- GEMM
// C[M,N] = A[M,K](bf16) @ Wt[N,K](bf16)^T [+bias] [relu] [+res] -> f32/bf16
// tile 64x64, BK=32, 4 waves. LDS rows padded to 40 (80B) for bank spread.
template <bool RELU, bool RES, bool OUTB>
__global__ __launch_bounds__(256) void gemm_kernel(
    const bf16* __restrict__ A, const bf16* __restrict__ Wt,
    const float* __restrict__ bias, const float* __restrict__ res,
    float* __restrict__ outF, bf16* __restrict__ outB, int K, int N) {
  __shared__ bf16 As[64][40];
  __shared__ bf16 Bs[64][40];
  int tid = threadIdx.x;
  int wave = tid >> 6, lane = tid & 63;
  int lr = lane & 15, lg = lane >> 4;
  int m0 = blockIdx.x * 64, n0 = blockIdx.y * 64;   // m-fast for W L2 reuse
  f32x4 acc[4] = {};
  int sr = tid >> 2, sc = (tid & 3) * 8;
  int mrow = wave * 16 + lr;

  const bf16* aptr = A + (size_t)(m0 + sr) * K + sc;
  const bf16* bptr = Wt + (size_t)(n0 + sr) * K + sc;
  for (int k0 = 0; k0 < K; k0 += 32) {
    bf16x8 av = *(const bf16x8*)(aptr + k0);
    bf16x8 bv = *(const bf16x8*)(bptr + k0);
    __syncthreads();                 // protect previous iteration's reads
    *(bf16x8*)&As[sr][sc] = av;
    *(bf16x8*)&Bs[sr][sc] = bv;
    __syncthreads();
    bf16x8 af = *(const bf16x8*)&As[mrow][lg * 8];
#pragma unroll
    for (int nt = 0; nt < 4; ++nt) {
      bf16x8 bfr = *(const bf16x8*)&Bs[nt * 16 + lr][lg * 8];
      acc[nt] = __builtin_amdgcn_mfma_f32_16x16x32_bf16(af, bfr, acc[nt], 0, 0, 0);
    }
  }

  // epilogue: D[m][n]: col = lane&15, row = (lane>>4)*4 + i
  int rb = wave * 16 + lg * 4;
#pragma unroll
  for (int nt = 0; nt < 4; ++nt) {
    int n = n0 + nt * 16 + lr;
    float bval = bias ? bias[n] : 0.0f;
#pragma unroll
    for (int i = 0; i < 4; ++i) {
      int m = m0 + rb + i;
      float val = acc[nt][i] + bval;
      if (RELU) val = fmaxf(val, 0.0f);
      if (RES) val += res[(size_t)m * N + n];
      if (OUTB) outB[(size_t)m * N + n] = (bf16)val;
      else      outF[(size_t)m * N + n] = val;
    }
  }
}

// ---------------------------------------------------------------- flash attn
// Block: 4 waves, 64 q-rows of one (b,h). KV tiles of 32.
// qkv packed [NTOK][1536] bf16 (q|k|v). att [NTOK][512] bf16.
__global__ __launch_bounds__(256) void fattn_kernel(
    const bf16* __restrict__ qkv, bf16* __restrict__ att) {
  __shared__ bf16 Ks[32][72];
  __shared__ bf16 Vt[64][40];    // [d][kv], XOR-swizzled cols
  __shared__ bf16 Pl[4][16][40];
  int tid = threadIdx.x;
  int wave = tid >> 6, lane = tid & 63;
  int lr = lane & 15, lg = lane >> 4;
  int qt0 = blockIdx.x * 64;
  int h = blockIdx.y, b = blockIdx.z;
  const bf16* qb = qkv + ((size_t)b * SEQ) * QS + h * HSZ;
  const bf16* kp = qb + DIM;
  const bf16* vp = qb + 2 * DIM;

  // Q fragments (A layout: row = lane&15, k-octet = (lane>>4)*8)
  bf16x8 aq[2];
  {
    const bf16* qr = qb + (size_t)(qt0 + wave * 16 + lr) * QS + lg * 8;
    aq[0] = *(const bf16x8*)qr;
    aq[1] = *(const bf16x8*)(qr + 32);
  }

  f32x4 accO[4] = {};
  float m_r[4] = {-1e30f, -1e30f, -1e30f, -1e30f};
  float l_r[4] = {0.f, 0.f, 0.f, 0.f};

  int srow = tid >> 3, sd0 = (tid & 7) * 8;
  int ntile = qt0 / 32 + 2;
  for (int ti = 0; ti < ntile; ++ti) {
    int kv0 = ti * 32;
    bf16x8 kv8 = *(const bf16x8*)(kp + (size_t)(kv0 + srow) * QS + sd0);
    bf16x8 vv8 = *(const bf16x8*)(vp + (size_t)(kv0 + srow) * QS + sd0);
    __syncthreads();   // prior tile's LDS reads done
    *(bf16x8*)&Ks[srow][sd0] = kv8;
#pragma unroll
    for (int j = 0; j < 8; ++j) {
      int row = sd0 + j;     // d index
      int cb2 = (srow * 2) ^ (((row >> 3) & 3) << 4);
      *(bf16*)((char*)Vt + row * 80 + cb2) = vv8[j];
    }
    __syncthreads();   // tile staged

    // S = Q K^T : per wave 16x32 scores
    f32x4 sc[2];
#pragma unroll
    for (int s = 0; s < 2; ++s) {
      bf16x8 b0 = *(const bf16x8*)&Ks[s * 16 + lr][lg * 8];
      bf16x8 b1 = *(const bf16x8*)&Ks[s * 16 + lr][32 + lg * 8];
      f32x4 z = {};
      z = __builtin_amdgcn_mfma_f32_16x16x32_bf16(aq[0], b0, z, 0, 0, 0);
      sc[s] = __builtin_amdgcn_mfma_f32_16x16x32_bf16(aq[1], b1, z, 0, 0, 0);
    }

    // mask + online softmax (C layout: row = lg*4+i, col = lr)
#pragma unroll
    for (int i = 0; i < 4; ++i) {
      int qrow = qt0 + wave * 16 + lg * 4 + i;
#pragma unroll
      for (int s = 0; s < 2; ++s) {
        int kvc = kv0 + s * 16 + lr;
        float val = sc[s][i] * 0.125f;
        sc[s][i] = (kvc <= qrow) ? val : -1e30f;
      }
      float t = fmaxf(sc[0][i], sc[1][i]);
      t = fmaxf(t, __shfl_xor(t, 1, 64));
      t = fmaxf(t, __shfl_xor(t, 2, 64));
      t = fmaxf(t, __shfl_xor(t, 4, 64));
      t = fmaxf(t, __shfl_xor(t, 8, 64));
      float mn = fmaxf(m_r[i], t);
      float alpha = __expf(m_r[i] - mn);
      m_r[i] = mn;
      float p0 = __expf(sc[0][i] - mn);
      float p1 = __expf(sc[1][i] - mn);
      sc[0][i] = p0; sc[1][i] = p1;
      float rs = p0 + p1;
      rs += __shfl_xor(rs, 1, 64);
      rs += __shfl_xor(rs, 2, 64);
      rs += __shfl_xor(rs, 4, 64);
      rs += __shfl_xor(rs, 8, 64);
      l_r[i] = l_r[i] * alpha + rs;
#pragma unroll
      for (int ds = 0; ds < 4; ++ds) accO[ds][i] *= alpha;
    }

    // P: C layout -> LDS (wave-private) -> A fragment
#pragma unroll
    for (int i = 0; i < 4; ++i) {
      Pl[wave][lg * 4 + i][lr]      = (bf16)sc[0][i];
      Pl[wave][lg * 4 + i][16 + lr] = (bf16)sc[1][i];
    }
    bf16x8 pa = *(const bf16x8*)&Pl[wave][lr][lg * 8];

#pragma unroll
    for (int ds = 0; ds < 4; ++ds) {
      int row = ds * 16 + lr;
      bf16x8 bv = *(const bf16x8*)((char*)Vt + row * 80 +
                                   ((lg * 16) ^ (((row >> 3) & 3) << 4)));
      accO[ds] = __builtin_amdgcn_mfma_f32_16x16x32_bf16(pa, bv, accO[ds], 0, 0, 0);
    }
  }

  // epilogue: O / l -> bf16
#pragma unroll
  for (int i = 0; i < 4; ++i) {
    float inv = 1.0f / l_r[i];
    size_t orow = ((size_t)b * SEQ + qt0 + wave * 16 + lg * 4 + i) * DIM + h * HSZ;
#pragma unroll
    for (int ds = 0; ds < 4; ++ds)
      att[orow + ds * 16 + lr] = (bf16)(accO[ds][i] * inv);
  }
}

// ---------------------------------------------------------------- launcher
extern "C" void kernel_launch(void* const* d_in, const int* in_sizes, int n_in,
                              void* d_out, int out_size, void* d_ws, size_t ws_size,
                              hipStream_t stream) {
  const int*   idx    = (const int*)d_in[0];
  const float* tok    = (const float*)d_in[1];
  const float* pos    = (const float*)d_in[2];
  const float* ln1_g  = (const float*)d_in[3];
  const float* ln1_b  = (const float*)d_in[4];
  const float* wq     = (const float*)d_in[5];
  const float* wk     = (const float*)d_in[6];
  const float* wv     = (const float*)d_in[7];
  const float* wo     = (const float*)d_in[8];
  const float* bo     = (const float*)d_in[9];
  const float* ln2_g  = (const float*)d_in[10];
  const float* ln2_b  = (const float*)d_in[11];
  const float* w1     = (const float*)d_in[12];
  const float* b1     = (const float*)d_in[13];
  const float* w2     = (const float*)d_in[14];
  const float* b2     = (const float*)d_in[15];
  const float* lnf_g  = (const float*)d_in[16];
  const float* lnf_b  = (const float*)d_in[17];
  const float* head_w = (const float*)d_in[18];
  const float* head_b = (const float*)d_in[19];

  char* W = (char*)d_ws;
  float* x     = (float*)(W);                 // [4096][512] f32   8,388,608 B
  bf16*  h     = (bf16*)(W + 8388608);        // [4096][512]       4,194,304
  bf16*  qkv   = (bf16*)(W + 12582912);       // [4096][1536]     12,582,912
  bf16*  attb  = (bf16*)(W + 25165824);       // [4096][512]       4,194,304
  bf16*  ffn   = (bf16*)(W + 29360128);       // [4096][2048]     16,777,216
  bf16*  wqkvT = (bf16*)(W + 46137344);       // 4L x [1536][512]  6,291,456
  bf16*  woT   = (bf16*)(W + 52428800);       // 4L x [512][512]   2,097,152
  bf16*  w1T   = (bf16*)(W + 54525952);       // 4L x [2048][512]  8,388,608
  bf16*  w2T   = (bf16*)(W + 62914560);       // 4L x [512][2048]  8,388,608
  bf16*  headT = (bf16*)(W + 71303168);       // [32000][512]     32,768,000  -> 104 MB

  // ---- weight transpose+cast passes (weights only; run first, pipeline) ----
  dim3 tDD(DIM / 32, DIM / 32);          // 512x512
  dim3 tF1(4 * DIM / 32, DIM / 32);      // -> [2048][512]
  dim3 tF2(DIM / 32, 4 * DIM / 32);      // -> [512][2048]
  dim3 tHD(VOC / 32, DIM / 32);          // -> [32000][512]
  for (int l = 0; l < NL; ++l) {
    size_t wOff = (size_t)l * DIM * DIM;
    wt_kernel<<<tDD, 256, 0, stream>>>(wq + wOff, wqkvT + (size_t)l * QS * DIM, DIM, DIM);
    wt_kernel<<<tDD, 256, 0, stream>>>(wk + wOff, wqkvT + (size_t)l * QS * DIM + DIM * DIM, DIM, DIM);
    wt_kernel<<<tDD, 256, 0, stream>>>(wv + wOff, wqkvT + (size_t)l * QS * DIM + 2 * DIM * DIM, DIM, DIM);
    wt_kernel<<<tDD, 256, 0, stream>>>(wo + wOff, woT + (size_t)l * DIM * DIM, DIM, DIM);
    wt_kernel<<<tF1, 256, 0, stream>>>(w1 + (size_t)l * DIM * 4 * DIM,
                                       w1T + (size_t)l * 4 * DIM * DIM, DIM, 4 * DIM);
    wt_kernel<<<tF2, 256, 0, stream>>>(w2 + (size_t)l * 4 * DIM * DIM,
                                       w2T + (size_t)l * 4 * DIM * DIM, 4 * DIM, DIM);
  }
  wt_kernel<<<tHD, 256, 0, stream>>>(head_w, headT, DIM, VOC);

  embed_kernel<<<NTOK * DIM / 256, 256, 0, stream>>>(idx, tok, pos, x);

  dim3 gQKV(NTOK / 64, QS / 64);        // (64, 24)
  dim3 gD(NTOK / 64, DIM / 64);         // (64, 8)
  dim3 gF(NTOK / 64, 4 * DIM / 64);     // (64, 32)
  dim3 gV(NTOK / 64, VOC / 64);         // (64, 500)
  dim3 gA(SEQ / 64, NH, NB);            // (32, 8, 2)

  for (int l = 0; l < NL; ++l) {
    ln_kernel<<<NTOK, 256, 0, stream>>>(x, ln1_g + l * DIM, ln1_b + l * DIM, h);
    gemm_kernel<false, false, true><<<gQKV, 256, 0, stream>>>(
        h, wqkvT + (size_t)l * QS * DIM, nullptr, nullptr, nullptr, qkv, DIM, QS);
    fattn_kernel<<<gA, 256, 0, stream>>>(qkv, attb);
    gemm_kernel<false, true, false><<<gD, 256, 0, stream>>>(
        attb, woT + (size_t)l * DIM * DIM, bo + l * DIM, x, x, nullptr, DIM, DIM);
    ln_kernel<<<NTOK, 256, 0, stream>>>(x, ln2_g + l * DIM, ln2_b + l * DIM, h);
    gemm_kernel<true, false, true><<<gF, 256, 0, stream>>>(
        h, w1T + (size_t)l * 4 * DIM * DIM, b1 + (size_t)l * 4 * DIM, nullptr,
        nullptr, ffn, DIM, 4 * DIM);
    gemm_kernel<false, true, false><<<gD, 256, 0, stream>>>(
        ffn, w2T + (size_t)l * 4 * DIM * DIM, b2 + l * DIM, x, x, nullptr,
        4 * DIM, DIM);
  }

  ln_kernel<<<NTOK, 256, 0, stream>>>(x, lnf_g, lnf_b, h);
  gemm_kernel<false, false, false><<<gV, 256, 0, stream>>>(
      h, headT, head_b, nullptr, (float*)d_out, nullptr, DIM, VOC);
}

// Round 5
// 1176.191 us; speedup vs baseline: 6.7598x; 1.0186x over previous
//
#include <hip/hip_runtime.h>
#include <hip/hip_bf16.h>
#include <cstddef>

typedef __bf16 bf16;
typedef __attribute__((ext_vector_type(8))) __bf16 bf16x8;
typedef __attribute__((ext_vector_type(4))) float f32x4;

constexpr int VOC = 32000;
constexpr int DIM = 512;
constexpr int NH  = 8;
constexpr int HSZ = 64;
constexpr int SEQ = 2048;
constexpr int NB  = 2;
constexpr int NL  = 4;
constexpr int NTOK = NB * SEQ;  // 4096 rows
constexpr int QS  = 3 * DIM;    // packed qkv row stride

// async global->LDS, 16B per lane (wave-uniform LDS base + lane*16)
__device__ __forceinline__ void gload16(const void* g, void* lds) {
  __builtin_amdgcn_global_load_lds(
      (const __attribute__((address_space(1))) unsigned int*)g,
      (__attribute__((address_space(3))) unsigned int*)lds, 16, 0, 0);
}

// ---------------------------------------------------------------- embedding
__global__ __launch_bounds__(256) void embed_kernel(
    const int* __restrict__ idx, const float* __restrict__ tok,
    const float* __restrict__ pos, float* __restrict__ x) {
  int i = blockIdx.x * 256 + threadIdx.x;   // over NTOK*DIM
  int row = i >> 9;                         // / DIM
  int d = i & (DIM - 1);
  int t = row & (SEQ - 1);
  int tk = idx[row];
  x[i] = tok[(size_t)tk * DIM + d] + pos[(size_t)t * DIM + d];
}

// ------------------------------------------------- weight transpose + cast
// w [K][N] f32  ->  wt [N][K] bf16   (32x32 tiles, 256 threads)
__global__ __launch_bounds__(256) void wt_kernel(
    const float* __restrict__ w, bf16* __restrict__ wt, int K, int N) {
  __shared__ float t[32][33];
  int n0 = blockIdx.x * 32, k0 = blockIdx.y * 32;
  int tx = threadIdx.x & 31, ty = threadIdx.x >> 5;
#pragma unroll
  for (int r = 0; r < 4; ++r)
    t[ty + r * 8][tx] = w[(size_t)(k0 + ty + r * 8) * N + n0 + tx];
  __syncthreads();
#pragma unroll
  for (int r = 0; r < 4; ++r)
    wt[(size_t)(n0 + ty + r * 8) * K + k0 + tx] = (bf16)t[tx][ty + r * 8];
}

// ---------------------------------------------------------------- layernorm
__global__ __launch_bounds__(256) void ln_kernel(
    const float* __restrict__ x, const float* __restrict__ g,
    const float* __restrict__ b, bf16* __restrict__ out) {
  __shared__ float s1[256], s2[256];
  int row = blockIdx.x;
  int tid = threadIdx.x;
  const float* xr = x + (size_t)row * DIM;
  float a0 = xr[tid], a1 = xr[tid + 256];
  s1[tid] = a0 + a1;
  s2[tid] = a0 * a0 + a1 * a1;
  __syncthreads();
  for (int off = 128; off > 0; off >>= 1) {
    if (tid < off) { s1[tid] += s1[tid + off]; s2[tid] += s2[tid + off]; }
    __syncthreads();
  }
  float mu = s1[0] * (1.0f / DIM);
  float var = s2[0] * (1.0f / DIM) - mu * mu;
  float rs = rsqrtf(var + 1e-5f);
  out[(size_t)row * DIM + tid] = (bf16)((a0 - mu) * rs * g[tid] + b[tid]);
  out[(size_t)row * DIM + tid + 256] =
      (bf16)((a1 - mu) * rs * g[tid + 256] + b[tid + 256]);
}

// ---------------------------------------------------------------- GEMM 128x128
// C[M,N] = A[M,K](bf16) @ Wt[N,K](bf16)^T [+bias] [relu] [+res] -> f32/bf16
// m97 structure: BK=64, global_load_lds(16B), 4 waves, acc 4x4, 2 barriers/iter.
// LDS XOR-swizzle (byte ^= (row&7)<<4) applied on read AND on the staged
// global SOURCE address (rule #21: gload_lds writes linearly).
template <bool RELU, bool RES, bool OUTB>
__global__ __launch_bounds__(256) void gemm128(
    const bf16* __restrict__ A, const bf16* __restrict__ Wt,
    const float* __restrict__ bias, const float* __restrict__ res,
    float* __restrict__ outF, bf16* __restrict__ outB, int K, int N) {
  __shared__ bf16 As[128 * 64];
  __shared__ bf16 Bs[128 * 64];
  int tid = threadIdx.x;
  int wv = tid >> 6, ln = tid & 63;
  int lr = ln & 15, lg = ln >> 4;
  // bijective XCD swizzle (nwg % 8 == 0 for all our grids), m-fast preserved
  int bid = blockIdx.y * 32 + blockIdx.x;           // gridDim.x == 32 always
  int cpx = gridDim.y * 4;                          // nwg/8
  int swz = (bid & 7) * cpx + (bid >> 3);
  int m0 = (swz & 31) * 128;
  int n0 = (swz >> 5) * 128;
  int wr = wv >> 1, wc = wv & 1;
  f32x4 acc[4][4] = {};

  const char* Ab = (const char*)A;
  const char* Bb = (const char*)Wt;

  for (int k0 = 0; k0 < K; k0 += 64) {
    __syncthreads();              // previous tile's reads complete
#pragma unroll
    for (int j = 0; j < 4; ++j) {
      int Lb = j * 4096 + wv * 1024;      // wave-uniform LDS byte base
      int L = Lb + ln * 16;
      int row = L >> 7;                   // tile row
      int colb = (L & 127) ^ ((row & 7) << 4);   // inverse-swizzled source col
      gload16(Ab + (size_t)(m0 + row) * (K * 2) + (size_t)k0 * 2 + colb,
              (char*)As + Lb);
      gload16(Bb + (size_t)(n0 + row) * (K * 2) + (size_t)k0 * 2 + colb,
              (char*)Bs + Lb);
    }
    __syncthreads();              // staged (compiler inserts vmcnt(0))
#pragma unroll
    for (int kk = 0; kk < 2; ++kk) {
      bf16x8 am[4], bn[4];
#pragma unroll
      for (int m = 0; m < 4; ++m) {
        int row = wr * 64 + m * 16 + lr;
        int cb = (kk * 64 + lg * 16) ^ ((row & 7) << 4);
        am[m] = *(const bf16x8*)((const char*)As + row * 128 + cb);
      }
#pragma unroll
      for (int n = 0; n < 4; ++n) {
        int row = wc * 64 + n * 16 + lr;
        int cb = (kk * 64 + lg * 16) ^ ((row & 7) << 4);
        bn[n] = *(const bf16x8*)((const char*)Bs + row * 128 + cb);
      }
#pragma unroll
      for (int m = 0; m < 4; ++m)
#pragma unroll
        for (int n = 0; n < 4; ++n)
          acc[m][n] = __builtin_amdgcn_mfma_f32_16x16x32_bf16(
              am[m], bn[n], acc[m][n], 0, 0, 0);
    }
  }

  // epilogue: D[m][n]: col = lane&15, row = (lane>>4)*4 + i
#pragma unroll
  for (int m = 0; m < 4; ++m) {
    int mrow = m0 + wr * 64 + m * 16 + lg * 4;
#pragma unroll
    for (int n = 0; n < 4; ++n) {
      int nc = n0 + wc * 64 + n * 16 + lr;
      float bval = bias ? bias[nc] : 0.0f;
#pragma unroll
      for (int i = 0; i < 4; ++i) {
        int mm = mrow + i;
        float val = acc[m][n][i] + bval;
        if (RELU) val = fmaxf(val, 0.0f);
        if (RES) val += res[(size_t)mm * N + nc];
        if (OUTB) outB[(size_t)mm * N + nc] = (bf16)val;
        else      outF[(size_t)mm * N + nc] = val;
      }
    }
  }
}

// ---------------------------------------------------------------- flash attn
// Block: 4 waves, 64 q-rows of one (b,h). KV tiles of 32.
// qkv packed [NTOK][1536] bf16 (q|k|v). att [NTOK][512] bf16.
__global__ __launch_bounds__(256) void fattn_kernel(
    const bf16* __restrict__ qkv, bf16* __restrict__ att) {
  __shared__ bf16 Ks[32][72];
  __shared__ bf16 Vt[64][40];    // [d][kv], XOR-swizzled cols
  __shared__ bf16 Pl[4][16][40];
  int tid = threadIdx.x;
  int wave = tid >> 6, lane = tid & 63;
  int lr = lane & 15, lg = lane >> 4;
  int qt0 = blockIdx.x * 64;
  int h = blockIdx.y, b = blockIdx.z;
  const bf16* qb = qkv + ((size_t)b * SEQ) * QS + h * HSZ;
  const bf16* kp = qb + DIM;
  const bf16* vp = qb + 2 * DIM;

  // Q fragments (A layout: row = lane&15, k-octet = (lane>>4)*8)
  bf16x8 aq[2];
  {
    const bf16* qr = qb + (size_t)(qt0 + wave * 16 + lr) * QS + lg * 8;
    aq[0] = *(const bf16x8*)qr;
    aq[1] = *(const bf16x8*)(qr + 32);
  }

  f32x4 accO[4] = {};
  float m_r[4] = {-1e30f, -1e30f, -1e30f, -1e30f};
  float l_r[4] = {0.f, 0.f, 0.f, 0.f};

  int srow = tid >> 3, sd0 = (tid & 7) * 8;
  int ntile = qt0 / 32 + 2;
  for (int ti = 0; ti < ntile; ++ti) {
    int kv0 = ti * 32;
    bf16x8 kv8 = *(const bf16x8*)(kp + (size_t)(kv0 + srow) * QS + sd0);
    bf16x8 vv8 = *(const bf16x8*)(vp + (size_t)(kv0 + srow) * QS + sd0);
    __syncthreads();   // prior tile's LDS reads done
    *(bf16x8*)&Ks[srow][sd0] = kv8;
#pragma unroll
    for (int j = 0; j < 8; ++j) {
      int row = sd0 + j;     // d index
      int cb2 = (srow * 2) ^ (((row >> 3) & 3) << 4);
      *(bf16*)((char*)Vt + row * 80 + cb2) = vv8[j];
    }
    __syncthreads();   // tile staged

    // S = Q K^T : per wave 16x32 scores
    f32x4 sc[2];
#pragma unroll
    for (int s = 0; s < 2; ++s) {
      bf16x8 b0 = *(const bf16x8*)&Ks[s * 16 + lr][lg * 8];
      bf16x8 b1 = *(const bf16x8*)&Ks[s * 16 + lr][32 + lg * 8];
      f32x4 z = {};
      z = __builtin_amdgcn_mfma_f32_16x16x32_bf16(aq[0], b0, z, 0, 0, 0);
      sc[s] = __builtin_amdgcn_mfma_f32_16x16x32_bf16(aq[1], b1, z, 0, 0, 0);
    }

    // mask + online softmax (C layout: row = lg*4+i, col = lr)
#pragma unroll
    for (int i = 0; i < 4; ++i) {
      int qrow = qt0 + wave * 16 + lg * 4 + i;
#pragma unroll
      for (int s = 0; s < 2; ++s) {
        int kvc = kv0 + s * 16 + lr;
        float val = sc[s][i] * 0.125f;
        sc[s][i] = (kvc <= qrow) ? val : -1e30f;
      }
      float t = fmaxf(sc[0][i], sc[1][i]);
      t = fmaxf(t, __shfl_xor(t, 1, 64));
      t = fmaxf(t, __shfl_xor(t, 2, 64));
      t = fmaxf(t, __shfl_xor(t, 4, 64));
      t = fmaxf(t, __shfl_xor(t, 8, 64));
      float mn = fmaxf(m_r[i], t);
      float alpha = __expf(m_r[i] - mn);
      m_r[i] = mn;
      float p0 = __expf(sc[0][i] - mn);
      float p1 = __expf(sc[1][i] - mn);
      sc[0][i] = p0; sc[1][i] = p1;
      float rs = p0 + p1;
      rs += __shfl_xor(rs, 1, 64);
      rs += __shfl_xor(rs, 2, 64);
      rs += __shfl_xor(rs, 4, 64);
      rs += __shfl_xor(rs, 8, 64);
      l_r[i] = l_r[i] * alpha + rs;
#pragma unroll
      for (int ds = 0; ds < 4; ++ds) accO[ds][i] *= alpha;
    }

    // P: C layout -> LDS (wave-private) -> A fragment
#pragma unroll
    for (int i = 0; i < 4; ++i) {
      Pl[wave][lg * 4 + i][lr]      = (bf16)sc[0][i];
      Pl[wave][lg * 4 + i][16 + lr] = (bf16)sc[1][i];
    }
    bf16x8 pa = *(const bf16x8*)&Pl[wave][lr][lg * 8];

#pragma unroll
    for (int ds = 0; ds < 4; ++ds) {
      int row = ds * 16 + lr;
      bf16x8 bv = *(const bf16x8*)((char*)Vt + row * 80 +
                                   ((lg * 16) ^ (((row >> 3) & 3) << 4)));
      accO[ds] = __builtin_amdgcn_mfma_f32_16x16x32_bf16(pa, bv, accO[ds], 0, 0, 0);
    }
  }

  // epilogue: O / l -> bf16
#pragma unroll
  for (int i = 0; i < 4; ++i) {
    float inv = 1.0f / l_r[i];
    size_t orow = ((size_t)b * SEQ + qt0 + wave * 16 + lg * 4 + i) * DIM + h * HSZ;
#pragma unroll
    for (int ds = 0; ds < 4; ++ds)
      att[orow + ds * 16 + lr] = (bf16)(accO[ds][i] * inv);
  }
}

// ---------------------------------------------------------------- launcher
extern "C" void kernel_launch(void* const* d_in, const int* in_sizes, int n_in,
                              void* d_out, int out_size, void* d_ws, size_t ws_size,
                              hipStream_t stream) {
  const int*   idx    = (const int*)d_in[0];
  const float* tok    = (const float*)d_in[1];
  const float* pos    = (const float*)d_in[2];
  const float* ln1_g  = (const float*)d_in[3];
  const float* ln1_b  = (const float*)d_in[4];
  const float* wq     = (const float*)d_in[5];
  const float* wk     = (const float*)d_in[6];
  const float* wv     = (const float*)d_in[7];
  const float* wo     = (const float*)d_in[8];
  const float* bo     = (const float*)d_in[9];
  const float* ln2_g  = (const float*)d_in[10];
  const float* ln2_b  = (const float*)d_in[11];
  const float* w1     = (const float*)d_in[12];
  const float* b1     = (const float*)d_in[13];
  const float* w2     = (const float*)d_in[14];
  const float* b2     = (const float*)d_in[15];
  const float* lnf_g  = (const float*)d_in[16];
  const float* lnf_b  = (const float*)d_in[17];
  const float* head_w = (const float*)d_in[18];
  const float* head_b = (const float*)d_in[19];

  char* W = (char*)d_ws;
  float* x     = (float*)(W);                 // [4096][512] f32   8,388,608 B
  bf16*  h     = (bf16*)(W + 8388608);        // [4096][512]       4,194,304
  bf16*  qkv   = (bf16*)(W + 12582912);       // [4096][1536]     12,582,912
  bf16*  attb  = (bf16*)(W + 25165824);       // [4096][512]       4,194,304
  bf16*  ffn   = (bf16*)(W + 29360128);       // [4096][2048]     16,777,216
  bf16*  wqkvT = (bf16*)(W + 46137344);       // 4L x [1536][512]  6,291,456
  bf16*  woT   = (bf16*)(W + 52428800);       // 4L x [512][512]   2,097,152
  bf16*  w1T   = (bf16*)(W + 54525952);       // 4L x [2048][512]  8,388,608
  bf16*  w2T   = (bf16*)(W + 62914560);       // 4L x [512][2048]  8,388,608
  bf16*  headT = (bf16*)(W + 71303168);       // [32000][512]     32,768,000  -> 104 MB

  // ---- weight transpose+cast passes ----
  dim3 tDD(DIM / 32, DIM / 32);
  dim3 tF1(4 * DIM / 32, DIM / 32);
  dim3 tF2(DIM / 32, 4 * DIM / 32);
  dim3 tHD(VOC / 32, DIM / 32);
  for (int l = 0; l < NL; ++l) {
    size_t wOff = (size_t)l * DIM * DIM;
    wt_kernel<<<tDD, 256, 0, stream>>>(wq + wOff, wqkvT + (size_t)l * QS * DIM, DIM, DIM);
    wt_kernel<<<tDD, 256, 0, stream>>>(wk + wOff, wqkvT + (size_t)l * QS * DIM + DIM * DIM, DIM, DIM);
    wt_kernel<<<tDD, 256, 0, stream>>>(wv + wOff, wqkvT + (size_t)l * QS * DIM + 2 * DIM * DIM, DIM, DIM);
    wt_kernel<<<tDD, 256, 0, stream>>>(wo + wOff, woT + (size_t)l * DIM * DIM, DIM, DIM);
    wt_kernel<<<tF1, 256, 0, stream>>>(w1 + (size_t)l * DIM * 4 * DIM,
                                       w1T + (size_t)l * 4 * DIM * DIM, DIM, 4 * DIM);
    wt_kernel<<<tF2, 256, 0, stream>>>(w2 + (size_t)l * 4 * DIM * DIM,
                                       w2T + (size_t)l * 4 * DIM * DIM, 4 * DIM, DIM);
  }
  wt_kernel<<<tHD, 256, 0, stream>>>(head_w, headT, DIM, VOC);

  embed_kernel<<<NTOK * DIM / 256, 256, 0, stream>>>(idx, tok, pos, x);

  dim3 gQKV(NTOK / 128, QS / 128);        // (32, 12)
  dim3 gD(NTOK / 128, DIM / 128);         // (32, 4)
  dim3 gF(NTOK / 128, 4 * DIM / 128);     // (32, 16)
  dim3 gV(NTOK / 128, VOC / 128);         // (32, 250)
  dim3 gA(SEQ / 64, NH, NB);              // (32, 8, 2)

  for (int l = 0; l < NL; ++l) {
    ln_kernel<<<NTOK, 256, 0, stream>>>(x, ln1_g + l * DIM, ln1_b + l * DIM, h);
    gemm128<false, false, true><<<gQKV, 256, 0, stream>>>(
        h, wqkvT + (size_t)l * QS * DIM, nullptr, nullptr, nullptr, qkv, DIM, QS);
    fattn_kernel<<<gA, 256, 0, stream>>>(qkv, attb);
    gemm128<false, true, false><<<gD, 256, 0, stream>>>(
        attb, woT + (size_t)l * DIM * DIM, bo + l * DIM, x, x, nullptr, DIM, DIM);
    ln_kernel<<<NTOK, 256, 0, stream>>>(x, ln2_g + l * DIM, ln2_b + l * DIM, h);
    gemm128<true, false, true><<<gF, 256, 0, stream>>>(
        h, w1T + (size_t)l * 4 * DIM * DIM, b1 + (size_t)l * 4 * DIM, nullptr,
        nullptr, ffn, DIM, 4 * DIM);
    gemm128<false, true, false><<<gD, 256, 0, stream>>>(
        ffn, w2T + (size_t)l * 4 * DIM * DIM, b2 + l * DIM, x, x, nullptr,
        4 * DIM, DIM);
  }

  ln_kernel<<<NTOK, 256, 0, stream>>>(x, lnf_g, lnf_b, h);
  gemm128<false, false, false><<<gV, 256, 0, stream>>>(
      h, headT, head_b, nullptr, (float*)d_out, nullptr, DIM, VOC);
}

// Round 6
// 1003.725 us; speedup vs baseline: 7.9213x; 1.1718x over previous
//
#include <hip/hip_runtime.h>
#include <hip/hip_bf16.h>
#include <cstddef>

typedef __bf16 bf16;
typedef __attribute__((ext_vector_type(8))) __bf16 bf16x8;
typedef __attribute__((ext_vector_type(4))) __bf16 bf16x4;
typedef __attribute__((ext_vector_type(4))) float f32x4;

constexpr int VOC = 32000;
constexpr int DIM = 512;
constexpr int NH  = 8;
constexpr int HSZ = 64;
constexpr int SEQ = 2048;
constexpr int NB  = 2;
constexpr int NL  = 4;
constexpr int NTOK = NB * SEQ;   // 4096 rows
constexpr int QS  = 3 * DIM;     // qkv weight N
constexpr int QKS = 2 * DIM;     // packed q|k row stride

// async global->LDS, 16B per lane (wave-uniform LDS base + lane*16)
__device__ __forceinline__ void gload16(const void* g, void* lds) {
  __builtin_amdgcn_global_load_lds(
      (const __attribute__((address_space(1))) unsigned int*)g,
      (__attribute__((address_space(3))) unsigned int*)lds, 16, 0, 0);
}

// ---------------------------------------------------------------- embedding
__global__ __launch_bounds__(256) void embed_kernel(
    const int* __restrict__ idx, const float* __restrict__ tok,
    const float* __restrict__ pos, float* __restrict__ x) {
  int i = blockIdx.x * 256 + threadIdx.x;
  int row = i >> 9;
  int d = i & (DIM - 1);
  int t = row & (SEQ - 1);
  int tk = idx[row];
  x[i] = tok[(size_t)tk * DIM + d] + pos[(size_t)t * DIM + d];
}

// ------------------------------------------------- ALL weight transposes in 1
// src [K][N] f32 -> dst [N][K] bf16, 32x32 tiles; blockIdx decodes matrix.
__global__ __launch_bounds__(256) void wt_all(
    const float* __restrict__ wq, const float* __restrict__ wk,
    const float* __restrict__ wv, const float* __restrict__ wo,
    const float* __restrict__ w1, const float* __restrict__ w2,
    const float* __restrict__ hw,
    bf16* __restrict__ wqkvT, bf16* __restrict__ woT,
    bf16* __restrict__ w1T, bf16* __restrict__ w2T, bf16* __restrict__ headT) {
  __shared__ float t[32][33];
  int bid = blockIdx.x;
  const float* src; bf16* dst; int K, N, n0, k0;
  if (bid < 12288) {
    int l = bid / 3072, tt = bid - l * 3072;
    if (tt < 1024) {            // wq/wk/wv/wo : 512x512, 256 tiles each
      int which = tt >> 8, u = tt & 255;
      K = DIM; N = DIM;
      n0 = (u & 15) * 32; k0 = (u >> 4) * 32;
      if (which == 0)      { src = wq + (size_t)l * DIM * DIM; dst = wqkvT + (size_t)l * QS * DIM; }
      else if (which == 1) { src = wk + (size_t)l * DIM * DIM; dst = wqkvT + (size_t)l * QS * DIM + DIM * DIM; }
      else if (which == 2) { src = wv + (size_t)l * DIM * DIM; dst = wqkvT + (size_t)l * QS * DIM + 2 * DIM * DIM; }
      else                 { src = wo + (size_t)l * DIM * DIM; dst = woT + (size_t)l * DIM * DIM; }
    } else if (tt < 2048) {     // w1: [512][2048] -> [2048][512]
      int u = tt - 1024;
      K = DIM; N = 4 * DIM;
      n0 = (u & 63) * 32; k0 = (u >> 6) * 32;
      src = w1 + (size_t)l * DIM * 4 * DIM; dst = w1T + (size_t)l * 4 * DIM * DIM;
    } else {                    // w2: [2048][512] -> [512][2048]
      int u = tt - 2048;
      K = 4 * DIM; N = DIM;
      n0 = (u & 15) * 32; k0 = (u >> 4) * 32;
      src = w2 + (size_t)l * 4 * DIM * DIM; dst = w2T + (size_t)l * 4 * DIM * DIM;
    }
  } else {                      // head: [512][32000] -> [32000][512]
    int u = bid - 12288;
    K = DIM; N = VOC;
    n0 = (u >> 4) * 32; k0 = (u & 15) * 32;
    src = hw; dst = headT;
  }
  int tx = threadIdx.x & 31, ty = threadIdx.x >> 5;
#pragma unroll
  for (int r = 0; r < 4; ++r)
    t[ty + r * 8][tx] = src[(size_t)(k0 + ty + r * 8) * N + n0 + tx];
  __syncthreads();
#pragma unroll
  for (int r = 0; r < 4; ++r)
    dst[(size_t)(n0 + ty + r * 8) * K + k0 + tx] = (bf16)t[tx][ty + r * 8];
}

// ---------------------------------------------------------------- layernorm
// 1 barrier: per-wave shfl reduce + 4-slot LDS combine
__global__ __launch_bounds__(256) void ln_kernel(
    const float* __restrict__ x, const float* __restrict__ g,
    const float* __restrict__ b, bf16* __restrict__ out) {
  __shared__ float s1[4], s2[4];
  int row = blockIdx.x, tid = threadIdx.x;
  int lane = tid & 63, w = tid >> 6;
  const float* xr = x + (size_t)row * DIM;
  float a0 = xr[tid], a1 = xr[tid + 256];
  float ps = a0 + a1, pq = a0 * a0 + a1 * a1;
#pragma unroll
  for (int m = 1; m < 64; m <<= 1) {
    ps += __shfl_xor(ps, m, 64);
    pq += __shfl_xor(pq, m, 64);
  }
  if (lane == 0) { s1[w] = ps; s2[w] = pq; }
  __syncthreads();
  float fs = s1[0] + s1[1] + s1[2] + s1[3];
  float fq = s2[0] + s2[1] + s2[2] + s2[3];
  float mu = fs * (1.0f / DIM);
  float var = fq * (1.0f / DIM) - mu * mu;
  float rs = rsqrtf(var + 1e-5f);
  out[(size_t)row * DIM + tid] = (bf16)((a0 - mu) * rs * g[tid] + b[tid]);
  out[(size_t)row * DIM + tid + 256] =
      (bf16)((a1 - mu) * rs * g[tid + 256] + b[tid + 256]);
}

// ---------------------------------------------------------------- GEMM 128x128
// m97 structure: BK=64, global_load_lds(16B), 4 waves, acc 4x4.
// XOR swizzle both-sides (rule #21). VSPLIT: n>=1024 blocks of the QKV GEMM
// write V transposed to vTout[b][h][d][t]; n<1024 -> outB stride ostride.
template <bool RELU, bool RES, bool OUTB, bool VSPLIT>
__global__ __launch_bounds__(256) void gemm128(
    const bf16* __restrict__ A, const bf16* __restrict__ Wt,
    const float* __restrict__ bias, const float* __restrict__ res,
    float* __restrict__ outF, bf16* __restrict__ outB, bf16* __restrict__ vTout,
    int K, int N, int ostride) {
  __shared__ bf16 As[128 * 64];
  __shared__ bf16 Bs[128 * 64];
  int tid = threadIdx.x;
  int wv = tid >> 6, ln = tid & 63;
  int lr = ln & 15, lg = ln >> 4;
  int bid = blockIdx.y * 32 + blockIdx.x;           // gridDim.x == 32 always
  int cpx = gridDim.y * 4;                          // nwg/8 (nwg % 8 == 0)
  int swz = (bid & 7) * cpx + (bid >> 3);
  int m0 = (swz & 31) * 128;
  int n0 = (swz >> 5) * 128;
  int wr = wv >> 1, wc = wv & 1;
  f32x4 acc[4][4] = {};

  const char* Ab = (const char*)A;
  const char* Bb = (const char*)Wt;

  for (int k0 = 0; k0 < K; k0 += 64) {
    __syncthreads();
#pragma unroll
    for (int j = 0; j < 4; ++j) {
      int Lb = j * 4096 + wv * 1024;
      int L = Lb + ln * 16;
      int row = L >> 7;
      int colb = (L & 127) ^ ((row & 7) << 4);
      gload16(Ab + (size_t)(m0 + row) * (K * 2) + (size_t)k0 * 2 + colb,
              (char*)As + Lb);
      gload16(Bb + (size_t)(n0 + row) * (K * 2) + (size_t)k0 * 2 + colb,
              (char*)Bs + Lb);
    }
    __syncthreads();
#pragma unroll
    for (int kk = 0; kk < 2; ++kk) {
      bf16x8 am[4], bn[4];
#pragma unroll
      for (int m = 0; m < 4; ++m) {
        int row = wr * 64 + m * 16 + lr;
        int cb = (kk * 64 + lg * 16) ^ ((row & 7) << 4);
        am[m] = *(const bf16x8*)((const char*)As + row * 128 + cb);
      }
#pragma unroll
      for (int n = 0; n < 4; ++n) {
        int row = wc * 64 + n * 16 + lr;
        int cb = (kk * 64 + lg * 16) ^ ((row & 7) << 4);
        bn[n] = *(const bf16x8*)((const char*)Bs + row * 128 + cb);
      }
#pragma unroll
      for (int m = 0; m < 4; ++m)
#pragma unroll
        for (int n = 0; n < 4; ++n)
          acc[m][n] = __builtin_amdgcn_mfma_f32_16x16x32_bf16(
              am[m], bn[n], acc[m][n], 0, 0, 0);
    }
  }

  if (VSPLIT && n0 >= 2 * DIM) {
    // V block of QKV: write transposed vT[b][h][d][t], 8B vector per (m,n)
#pragma unroll
    for (int m = 0; m < 4; ++m) {
      int mrow = m0 + wr * 64 + m * 16 + lg * 4;
      int bb = mrow >> 11, tt = mrow & (SEQ - 1);
#pragma unroll
      for (int n = 0; n < 4; ++n) {
        int d = n0 + wc * 64 + n * 16 + lr - 2 * DIM;
        bf16x4 pk;
#pragma unroll
        for (int i = 0; i < 4; ++i) pk[i] = (bf16)acc[m][n][i];
        *(bf16x4*)(vTout + ((size_t)(bb * NH + (d >> 6)) * HSZ + (d & 63)) * SEQ + tt) = pk;
      }
    }
    return;
  }

  // epilogue: D[m][n]: col = lane&15, row = (lane>>4)*4 + i
#pragma unroll
  for (int m = 0; m < 4; ++m) {
    int mrow = m0 + wr * 64 + m * 16 + lg * 4;
#pragma unroll
    for (int n = 0; n < 4; ++n) {
      int nc = n0 + wc * 64 + n * 16 + lr;
      float bval = bias ? bias[nc] : 0.0f;
#pragma unroll
      for (int i = 0; i < 4; ++i) {
        int mm = mrow + i;
        float val = acc[m][n][i] + bval;
        if (RELU) val = fmaxf(val, 0.0f);
        if (RES) val += res[(size_t)mm * ostride + nc];
        if (OUTB) outB[(size_t)mm * ostride + nc] = (bf16)val;
        else      outF[(size_t)mm * ostride + nc] = val;
      }
    }
  }
}

// ---------------------------------------------------------------- flash attn
// 4 waves, 64 q-rows/block, KVBLK=64. K from qk[t][1024] (k half),
// V pre-transposed vT[b][h][d][t]. Both staged via global_load_lds with
// both-sides XOR swizzle; 16 MFMA per 2 barriers per wave.
__global__ __launch_bounds__(256) void fattn_kernel(
    const bf16* __restrict__ qk, const bf16* __restrict__ vT,
    bf16* __restrict__ att) {
  __shared__ bf16 Ks[64 * 64];   // [kv][d], swizzled
  __shared__ bf16 Vs[64 * 64];   // [d][kv], swizzled
  __shared__ bf16 Pl[4][16][72];
  int tid = threadIdx.x;
  int wave = tid >> 6, lane = tid & 63;
  int lr = lane & 15, lg = lane >> 4;
  int qt0 = blockIdx.x * 64;
  int h = blockIdx.y, b = blockIdx.z;
  const bf16* qb = qk + ((size_t)b * SEQ) * QKS + h * HSZ;
  const char* kb = (const char*)(qb + DIM);
  const char* vb = (const char*)(vT + (size_t)(b * NH + h) * HSZ * SEQ);

  // Q A-fragments (row = lane&15, k-octet = (lane>>4)*8 [+32])
  bf16x8 aq[2];
  {
    const bf16* qr = qb + (size_t)(qt0 + wave * 16 + lr) * QKS + lg * 8;
    aq[0] = *(const bf16x8*)qr;
    aq[1] = *(const bf16x8*)(qr + 32);
  }

  f32x4 accO[4] = {};
  float m_r[4] = {-1e30f, -1e30f, -1e30f, -1e30f};
  float l_r[4] = {0.f, 0.f, 0.f, 0.f};

  int ntile = qt0 / 64 + 1;
  for (int ti = 0; ti < ntile; ++ti) {
    int kv0 = ti * 64;
    __syncthreads();
#pragma unroll
    for (int j = 0; j < 2; ++j) {
      int Lb = j * 4096 + wave * 1024;
      int L = Lb + lane * 16;
      int row = L >> 7;
      int cb = (L & 127) ^ ((row & 7) << 4);
      gload16(kb + (size_t)(kv0 + row) * (QKS * 2) + cb, (char*)Ks + Lb);
      gload16(vb + (size_t)row * (SEQ * 2) + kv0 * 2 + cb, (char*)Vs + Lb);
    }
    __syncthreads();

    // S = Q K^T : 16x64 scores per wave
    f32x4 sc[4];
#pragma unroll
    for (int s = 0; s < 4; ++s) {
      int row = s * 16 + lr;
      const char* base = (const char*)Ks + row * 128;
      bf16x8 b0 = *(const bf16x8*)(base + ((lg * 16) ^ ((row & 7) << 4)));
      bf16x8 b1 = *(const bf16x8*)(base + ((64 + lg * 16) ^ ((row & 7) << 4)));
      f32x4 z = {};
      z = __builtin_amdgcn_mfma_f32_16x16x32_bf16(aq[0], b0, z, 0, 0, 0);
      sc[s] = __builtin_amdgcn_mfma_f32_16x16x32_bf16(aq[1], b1, z, 0, 0, 0);
    }

    // mask + online softmax (C layout: row = lg*4+i, col = lr)
#pragma unroll
    for (int i = 0; i < 4; ++i) {
      int qrow = qt0 + wave * 16 + lg * 4 + i;
#pragma unroll
      for (int s = 0; s < 4; ++s) {
        int kvc = kv0 + s * 16 + lr;
        float val = sc[s][i] * 0.125f;
        sc[s][i] = (kvc <= qrow) ? val : -1e30f;
      }
      float t = fmaxf(fmaxf(sc[0][i], sc[1][i]), fmaxf(sc[2][i], sc[3][i]));
      t = fmaxf(t, __shfl_xor(t, 1, 64));
      t = fmaxf(t, __shfl_xor(t, 2, 64));
      t = fmaxf(t, __shfl_xor(t, 4, 64));
      t = fmaxf(t, __shfl_xor(t, 8, 64));
      float mn = fmaxf(m_r[i], t);
      float alpha = __expf(m_r[i] - mn);
      m_r[i] = mn;
      float rs = 0.f;
#pragma unroll
      for (int s = 0; s < 4; ++s) {
        float p = __expf(sc[s][i] - mn);
        sc[s][i] = p;
        rs += p;
      }
      rs += __shfl_xor(rs, 1, 64);
      rs += __shfl_xor(rs, 2, 64);
      rs += __shfl_xor(rs, 4, 64);
      rs += __shfl_xor(rs, 8, 64);
      l_r[i] = l_r[i] * alpha + rs;
#pragma unroll
      for (int ds = 0; ds < 4; ++ds) accO[ds][i] *= alpha;
    }

    // P: C layout -> wave-private LDS -> A fragments
#pragma unroll
    for (int i = 0; i < 4; ++i)
#pragma unroll
      for (int s = 0; s < 4; ++s)
        Pl[wave][lg * 4 + i][s * 16 + lr] = (bf16)sc[s][i];
    bf16x8 pa0 = *(const bf16x8*)&Pl[wave][lr][lg * 8];
    bf16x8 pa1 = *(const bf16x8*)&Pl[wave][lr][32 + lg * 8];

#pragma unroll
    for (int ds = 0; ds < 4; ++ds) {
      int row = ds * 16 + lr;
      const char* base = (const char*)Vs + row * 128;
      bf16x8 v0 = *(const bf16x8*)(base + ((lg * 16) ^ ((row & 7) << 4)));
      bf16x8 v1 = *(const bf16x8*)(base + ((64 + lg * 16) ^ ((row & 7) << 4)));
      accO[ds] = __builtin_amdgcn_mfma_f32_16x16x32_bf16(pa0, v0, accO[ds], 0, 0, 0);
      accO[ds] = __builtin_amdgcn_mfma_f32_16x16x32_bf16(pa1, v1, accO[ds], 0, 0, 0);
    }
  }

  // epilogue: O / l -> bf16, head-major [t][h*64+d]
#pragma unroll
  for (int i = 0; i < 4; ++i) {
    float inv = 1.0f / l_r[i];
    size_t orow = ((size_t)b * SEQ + qt0 + wave * 16 + lg * 4 + i) * DIM + h * HSZ;
#pragma unroll
    for (int ds = 0; ds < 4; ++ds)
      att[orow + ds * 16 + lr] = (bf16)(accO[ds][i] * inv);
  }
}

// ---------------------------------------------------------------- launcher
extern "C" void kernel_launch(void* const* d_in, const int* in_sizes, int n_in,
                              void* d_out, int out_size, void* d_ws, size_t ws_size,
                              hipStream_t stream) {
  const int*   idx    = (const int*)d_in[0];
  const float* tok    = (const float*)d_in[1];
  const float* pos    = (const float*)d_in[2];
  const float* ln1_g  = (const float*)d_in[3];
  const float* ln1_b  = (const float*)d_in[4];
  const float* wq     = (const float*)d_in[5];
  const float* wk     = (const float*)d_in[6];
  const float* wv     = (const float*)d_in[7];
  const float* wo     = (const float*)d_in[8];
  const float* bo     = (const float*)d_in[9];
  const float* ln2_g  = (const float*)d_in[10];
  const float* ln2_b  = (const float*)d_in[11];
  const float* w1     = (const float*)d_in[12];
  const float* b1     = (const float*)d_in[13];
  const float* w2     = (const float*)d_in[14];
  const float* b2     = (const float*)d_in[15];
  const float* lnf_g  = (const float*)d_in[16];
  const float* lnf_b  = (const float*)d_in[17];
  const float* head_w = (const float*)d_in[18];
  const float* head_b = (const float*)d_in[19];

  char* W = (char*)d_ws;
  float* x     = (float*)(W);                 // [4096][512] f32    8 MB
  bf16*  h     = (bf16*)(W + 8388608);        // [4096][512]        4 MB
  bf16*  qk    = (bf16*)(W + 12582912);       // [4096][1024]       8 MB
  bf16*  vTb   = (bf16*)(W + 20971520);       // [2][8][64][2048]   4 MB
  bf16*  attb  = (bf16*)(W + 25165824);       // [4096][512]        4 MB
  bf16*  ffn   = (bf16*)(W + 29360128);       // [4096][2048]      16 MB
  bf16*  wqkvT = (bf16*)(W + 46137344);       // 4L x [1536][512]   6 MB
  bf16*  woT   = (bf16*)(W + 52428800);       // 4L x [512][512]    2 MB
  bf16*  w1T   = (bf16*)(W + 54525952);       // 4L x [2048][512]   8 MB
  bf16*  w2T   = (bf16*)(W + 62914560);       // 4L x [512][2048]   8 MB
  bf16*  headT = (bf16*)(W + 71303168);       // [32000][512]      ~31.3 MB

  wt_all<<<12288 + 16000, 256, 0, stream>>>(wq, wk, wv, wo, w1, w2, head_w,
                                            wqkvT, woT, w1T, w2T, headT);
  embed_kernel<<<NTOK * DIM / 256, 256, 0, stream>>>(idx, tok, pos, x);

  dim3 gQKV(NTOK / 128, QS / 128);        // (32, 12)
  dim3 gD(NTOK / 128, DIM / 128);         // (32, 4)
  dim3 gF(NTOK / 128, 4 * DIM / 128);     // (32, 16)
  dim3 gV(NTOK / 128, VOC / 128);         // (32, 250)
  dim3 gA(SEQ / 64, NH, NB);              // (32, 8, 2)

  for (int l = 0; l < NL; ++l) {
    ln_kernel<<<NTOK, 256, 0, stream>>>(x, ln1_g + l * DIM, ln1_b + l * DIM, h);
    gemm128<false, false, true, true><<<gQKV, 256, 0, stream>>>(
        h, wqkvT + (size_t)l * QS * DIM, nullptr, nullptr, nullptr, qk, vTb,
        DIM, QS, QKS);
    fattn_kernel<<<gA, 256, 0, stream>>>(qk, vTb, attb);
    gemm128<false, true, false, false><<<gD, 256, 0, stream>>>(
        attb, woT + (size_t)l * DIM * DIM, bo + l * DIM, x, x, nullptr, nullptr,
        DIM, DIM, DIM);
    ln_kernel<<<NTOK, 256, 0, stream>>>(x, ln2_g + l * DIM, ln2_b + l * DIM, h);
    gemm128<true, false, true, false><<<gF, 256, 0, stream>>>(
        h, w1T + (size_t)l * 4 * DIM * DIM, b1 + (size_t)l * 4 * DIM, nullptr,
        nullptr, ffn, nullptr, DIM, 4 * DIM, 4 * DIM);
    gemm128<false, true, false, false><<<gD, 256, 0, stream>>>(
        ffn, w2T + (size_t)l * 4 * DIM * DIM, b2 + l * DIM, x, x, nullptr,
        nullptr, 4 * DIM, DIM, DIM);
  }

  ln_kernel<<<NTOK, 256, 0, stream>>>(x, lnf_g, lnf_b, h);
  gemm128<false, false, false, false><<<gV, 256, 0, stream>>>(
      h, headT, head_b, nullptr, (float*)d_out, nullptr, nullptr, DIM, VOC, VOC);
}

// Round 7
// 961.743 us; speedup vs baseline: 8.2671x; 1.0437x over previous
//
#include <hip/hip_runtime.h>
#include <hip/hip_bf16.h>
#include <cstddef>

typedef __bf16 bf16;
typedef __attribute__((ext_vector_type(8))) __bf16 bf16x8;
typedef __attribute__((ext_vector_type(4))) __bf16 bf16x4;
typedef __attribute__((ext_vector_type(4))) float f32x4;

constexpr int VOC = 32000;
constexpr int DIM = 512;
constexpr int NH  = 8;
constexpr int HSZ = 64;
constexpr int SEQ = 2048;
constexpr int NB  = 2;
constexpr int NL  = 4;
constexpr int NTOK = NB * SEQ;   // 4096 rows
constexpr int QS  = 3 * DIM;     // qkv weight N
constexpr int QKS = 2 * DIM;     // packed q|k row stride

// async global->LDS, 16B per lane (wave-uniform LDS base + lane*16)
__device__ __forceinline__ void gload16(const void* g, void* lds) {
  __builtin_amdgcn_global_load_lds(
      (const __attribute__((address_space(1))) unsigned int*)g,
      (__attribute__((address_space(3))) unsigned int*)lds, 16, 0, 0);
}

// ---------------------------------------------------------------- embedding
__global__ __launch_bounds__(256) void embed_kernel(
    const int* __restrict__ idx, const float* __restrict__ tok,
    const float* __restrict__ pos, float* __restrict__ x) {
  int i = blockIdx.x * 256 + threadIdx.x;
  int row = i >> 9;
  int d = i & (DIM - 1);
  int t = row & (SEQ - 1);
  int tk = idx[row];
  x[i] = tok[(size_t)tk * DIM + d] + pos[(size_t)t * DIM + d];
}

// ------------------------------------------------- ALL weight transposes in 1
__global__ __launch_bounds__(256) void wt_all(
    const float* __restrict__ wq, const float* __restrict__ wk,
    const float* __restrict__ wv, const float* __restrict__ wo,
    const float* __restrict__ w1, const float* __restrict__ w2,
    const float* __restrict__ hw,
    bf16* __restrict__ wqkvT, bf16* __restrict__ woT,
    bf16* __restrict__ w1T, bf16* __restrict__ w2T, bf16* __restrict__ headT) {
  __shared__ float t[32][33];
  int bid = blockIdx.x;
  const float* src; bf16* dst; int K, N, n0, k0;
  if (bid < 12288) {
    int l = bid / 3072, tt = bid - l * 3072;
    if (tt < 1024) {
      int which = tt >> 8, u = tt & 255;
      K = DIM; N = DIM;
      n0 = (u & 15) * 32; k0 = (u >> 4) * 32;
      if (which == 0)      { src = wq + (size_t)l * DIM * DIM; dst = wqkvT + (size_t)l * QS * DIM; }
      else if (which == 1) { src = wk + (size_t)l * DIM * DIM; dst = wqkvT + (size_t)l * QS * DIM + DIM * DIM; }
      else if (which == 2) { src = wv + (size_t)l * DIM * DIM; dst = wqkvT + (size_t)l * QS * DIM + 2 * DIM * DIM; }
      else                 { src = wo + (size_t)l * DIM * DIM; dst = woT + (size_t)l * DIM * DIM; }
    } else if (tt < 2048) {
      int u = tt - 1024;
      K = DIM; N = 4 * DIM;
      n0 = (u & 63) * 32; k0 = (u >> 6) * 32;
      src = w1 + (size_t)l * DIM * 4 * DIM; dst = w1T + (size_t)l * 4 * DIM * DIM;
    } else {
      int u = tt - 2048;
      K = 4 * DIM; N = DIM;
      n0 = (u & 15) * 32; k0 = (u >> 4) * 32;
      src = w2 + (size_t)l * 4 * DIM * DIM; dst = w2T + (size_t)l * 4 * DIM * DIM;
    }
  } else {
    int u = bid - 12288;
    K = DIM; N = VOC;
    n0 = (u >> 4) * 32; k0 = (u & 15) * 32;
    src = hw; dst = headT;
  }
  int tx = threadIdx.x & 31, ty = threadIdx.x >> 5;
#pragma unroll
  for (int r = 0; r < 4; ++r)
    t[ty + r * 8][tx] = src[(size_t)(k0 + ty + r * 8) * N + n0 + tx];
  __syncthreads();
#pragma unroll
  for (int r = 0; r < 4; ++r)
    dst[(size_t)(n0 + ty + r * 8) * K + k0 + tx] = (bf16)t[tx][ty + r * 8];
}

// ---------------------------------------------------------------- layernorm
__global__ __launch_bounds__(256) void ln_kernel(
    const float* __restrict__ x, const float* __restrict__ g,
    const float* __restrict__ b, bf16* __restrict__ out) {
  __shared__ float s1[4], s2[4];
  int row = blockIdx.x, tid = threadIdx.x;
  int lane = tid & 63, w = tid >> 6;
  const float* xr = x + (size_t)row * DIM;
  float a0 = xr[tid], a1 = xr[tid + 256];
  float ps = a0 + a1, pq = a0 * a0 + a1 * a1;
#pragma unroll
  for (int m = 1; m < 64; m <<= 1) {
    ps += __shfl_xor(ps, m, 64);
    pq += __shfl_xor(pq, m, 64);
  }
  if (lane == 0) { s1[w] = ps; s2[w] = pq; }
  __syncthreads();
  float fs = s1[0] + s1[1] + s1[2] + s1[3];
  float fq = s2[0] + s2[1] + s2[2] + s2[3];
  float mu = fs * (1.0f / DIM);
  float var = fq * (1.0f / DIM) - mu * mu;
  float rs = rsqrtf(var + 1e-5f);
  out[(size_t)row * DIM + tid] = (bf16)((a0 - mu) * rs * g[tid] + b[tid]);
  out[(size_t)row * DIM + tid + 256] =
      (bf16)((a1 - mu) * rs * g[tid + 256] + b[tid + 256]);
}

// ---------------------------------------------------------------- GEMM 128xBN
// m97 structure: BK=64, global_load_lds(16B), 4 waves. XOR swizzle both sides.
// BN=128: waves 2x2 (acc 4x4). BN=64: waves 4x1 (acc 2x4) -> 2x the wg count
// for N=512 GEMMs (occupancy fix). VSPLIT (BN=128 only): n>=1024 writes V
// transposed to vTout[b][h][d][t].
template <int BN, bool RELU, bool RES, bool OUTB, bool VSPLIT>
__global__ __launch_bounds__(256) void gemm128(
    const bf16* __restrict__ A, const bf16* __restrict__ Wt,
    const float* __restrict__ bias, const float* __restrict__ res,
    float* __restrict__ outF, bf16* __restrict__ outB, bf16* __restrict__ vTout,
    int K, int N, int ostride) {
  __shared__ bf16 As[128 * 64];
  __shared__ bf16 Bs[BN * 64];
  constexpr int WN = (BN == 128) ? 2 : 1;   // wave grid n
  constexpr int WM = 4 / WN;                // wave grid m
  constexpr int MP = 128 / WM / 16;         // m sub-tiles per wave
  constexpr int NP = BN / WN / 16;          // n sub-tiles per wave (=4)
  int tid = threadIdx.x;
  int wid = tid >> 6, ln = tid & 63;
  int lr = ln & 15, lg = ln >> 4;
  int bid = blockIdx.y * 32 + blockIdx.x;           // gridDim.x == 32 always
  int cpx = gridDim.y * 4;                          // nwg/8 (nwg % 8 == 0)
  int swz = (bid & 7) * cpx + (bid >> 3);
  int m0 = (swz & 31) * 128;
  int n0 = (swz >> 5) * BN;
  int wr = wid / WN, wc = wid % WN;
  f32x4 acc[MP][NP] = {};

  const char* Ab = (const char*)A;
  const char* Bb = (const char*)Wt;

  for (int k0 = 0; k0 < K; k0 += 64) {
    __syncthreads();
#pragma unroll
    for (int j = 0; j < 4; ++j) {
      int Lb = j * 4096 + wid * 1024;
      int L = Lb + ln * 16;
      int row = L >> 7;
      int colb = (L & 127) ^ ((row & 7) << 4);
      gload16(Ab + (size_t)(m0 + row) * (K * 2) + (size_t)k0 * 2 + colb,
              (char*)As + Lb);
    }
#pragma unroll
    for (int j = 0; j < BN / 32; ++j) {
      int Lb = j * 4096 + wid * 1024;
      int L = Lb + ln * 16;
      int row = L >> 7;
      int colb = (L & 127) ^ ((row & 7) << 4);
      gload16(Bb + (size_t)(n0 + row) * (K * 2) + (size_t)k0 * 2 + colb,
              (char*)Bs + Lb);
    }
    __syncthreads();
#pragma unroll
    for (int kk = 0; kk < 2; ++kk) {
      bf16x8 am[MP], bn[NP];
#pragma unroll
      for (int m = 0; m < MP; ++m) {
        int row = wr * (128 / WM) + m * 16 + lr;
        int cb = (kk * 64 + lg * 16) ^ ((row & 7) << 4);
        am[m] = *(const bf16x8*)((const char*)As + row * 128 + cb);
      }
#pragma unroll
      for (int n = 0; n < NP; ++n) {
        int row = wc * (BN / WN) + n * 16 + lr;
        int cb = (kk * 64 + lg * 16) ^ ((row & 7) << 4);
        bn[n] = *(const bf16x8*)((const char*)Bs + row * 128 + cb);
      }
#pragma unroll
      for (int m = 0; m < MP; ++m)
#pragma unroll
        for (int n = 0; n < NP; ++n)
          acc[m][n] = __builtin_amdgcn_mfma_f32_16x16x32_bf16(
              am[m], bn[n], acc[m][n], 0, 0, 0);
    }
  }

  if (VSPLIT && n0 >= 2 * DIM) {
#pragma unroll
    for (int m = 0; m < MP; ++m) {
      int mrow = m0 + wr * (128 / WM) + m * 16 + lg * 4;
      int bb = mrow >> 11, tt = mrow & (SEQ - 1);
#pragma unroll
      for (int n = 0; n < NP; ++n) {
        int d = n0 + wc * (BN / WN) + n * 16 + lr - 2 * DIM;
        bf16x4 pk;
#pragma unroll
        for (int i = 0; i < 4; ++i) pk[i] = (bf16)acc[m][n][i];
        *(bf16x4*)(vTout + ((size_t)(bb * NH + (d >> 6)) * HSZ + (d & 63)) * SEQ + tt) = pk;
      }
    }
    return;
  }

#pragma unroll
  for (int m = 0; m < MP; ++m) {
    int mrow = m0 + wr * (128 / WM) + m * 16 + lg * 4;
#pragma unroll
    for (int n = 0; n < NP; ++n) {
      int nc = n0 + wc * (BN / WN) + n * 16 + lr;
      float bval = bias ? bias[nc] : 0.0f;
#pragma unroll
      for (int i = 0; i < 4; ++i) {
        int mm = mrow + i;
        float val = acc[m][n][i] + bval;
        if (RELU) val = fmaxf(val, 0.0f);
        if (RES) val += res[(size_t)mm * ostride + nc];
        if (OUTB) outB[(size_t)mm * ostride + nc] = (bf16)val;
        else      outF[(size_t)mm * ostride + nc] = val;
      }
    }
  }
}

// ---------------------------------------------------------------- flash attn
// 4 waves, 64 q-rows/block, KVBLK=64, double-buffered K/V via global_load_lds
// with counted vmcnt(4) (loads fly under previous tile's compute). b==1 blocks
// reverse the q-tile map so each CU gets qt + (31-qt) => balanced work.
// Diagonal tile masked; interior tiles skip masking. Defer-max THR=8 (T13).
__global__ __launch_bounds__(256) void fattn_kernel(
    const bf16* __restrict__ qk, const bf16* __restrict__ vT,
    bf16* __restrict__ att) {
  __shared__ bf16 Ks[2][64 * 64];   // [kv][d], swizzled
  __shared__ bf16 Vs[2][64 * 64];   // [d][kv], swizzled
  __shared__ bf16 Pl[4][16][72];
  int tid = threadIdx.x;
  int wave = tid >> 6, lane = tid & 63;
  int lr = lane & 15, lg = lane >> 4;
  int h = blockIdx.y, b = blockIdx.z;
  int qt0 = ((b == 1) ? (gridDim.x - 1 - blockIdx.x) : blockIdx.x) * 64;
  const bf16* qb = qk + ((size_t)b * SEQ) * QKS + h * HSZ;
  const char* kb = (const char*)(qb + DIM);
  const char* vb = (const char*)(vT + (size_t)(b * NH + h) * HSZ * SEQ);

  // Q A-fragments (row = lane&15, k-octet = (lane>>4)*8 [+32])
  bf16x8 aq[2];
  {
    const bf16* qr = qb + (size_t)(qt0 + wave * 16 + lr) * QKS + lg * 8;
    aq[0] = *(const bf16x8*)qr;
    aq[1] = *(const bf16x8*)(qr + 32);
  }

  f32x4 accO[4] = {};
  float m_r[4] = {-1e30f, -1e30f, -1e30f, -1e30f};
  float l_r[4] = {0.f, 0.f, 0.f, 0.f};

  int ntile = qt0 / 64 + 1;
  // stage tile ti into buffer buf (4 gload16 per wave)
#define STAGE(ti, buf)                                                        \
  {                                                                           \
    _Pragma("unroll")                                                         \
    for (int j = 0; j < 2; ++j) {                                             \
      int Lb = j * 4096 + wave * 1024;                                        \
      int L = Lb + lane * 16;                                                 \
      int row = L >> 7;                                                       \
      int cb = (L & 127) ^ ((row & 7) << 4);                                  \
      gload16(kb + (size_t)((ti) * 64 + row) * (QKS * 2) + cb,                \
              (char*)Ks[buf] + Lb);                                           \
      gload16(vb + (size_t)row * (SEQ * 2) + (ti) * 128 + cb,                 \
              (char*)Vs[buf] + Lb);                                           \
    }                                                                         \
  }

  STAGE(0, 0);
  int cur = 0;
  for (int ti = 0; ti < ntile; ++ti) {
    if (ti + 1 < ntile) {
      STAGE(ti + 1, cur ^ 1);
      asm volatile("s_waitcnt vmcnt(4)" ::: "memory");
    } else {
      asm volatile("s_waitcnt vmcnt(0)" ::: "memory");
    }
    __builtin_amdgcn_s_barrier();
    int kv0 = ti * 64;
    bool diag = (ti == ntile - 1);

    // S = Q K^T : 16x64 scores per wave
    f32x4 sc[4];
#pragma unroll
    for (int s = 0; s < 4; ++s) {
      int row = s * 16 + lr;
      const char* base = (const char*)Ks[cur] + row * 128;
      bf16x8 b0 = *(const bf16x8*)(base + ((lg * 16) ^ ((row & 7) << 4)));
      bf16x8 b1 = *(const bf16x8*)(base + ((64 + lg * 16) ^ ((row & 7) << 4)));
      f32x4 z = {};
      z = __builtin_amdgcn_mfma_f32_16x16x32_bf16(aq[0], b0, z, 0, 0, 0);
      sc[s] = __builtin_amdgcn_mfma_f32_16x16x32_bf16(aq[1], b1, z, 0, 0, 0);
    }

    // softmax (C layout: row = lg*4+i, col = lr); defer-max THR=8
#pragma unroll
    for (int i = 0; i < 4; ++i) {
      if (diag) {
        int qrow = qt0 + wave * 16 + lg * 4 + i;
#pragma unroll
        for (int s = 0; s < 4; ++s) {
          int kvc = kv0 + s * 16 + lr;
          sc[s][i] = (kvc <= qrow) ? sc[s][i] * 0.125f : -1e30f;
        }
      } else {
#pragma unroll
        for (int s = 0; s < 4; ++s) sc[s][i] *= 0.125f;
      }
      float t = fmaxf(fmaxf(sc[0][i], sc[1][i]), fmaxf(sc[2][i], sc[3][i]));
      t = fmaxf(t, __shfl_xor(t, 1, 64));
      t = fmaxf(t, __shfl_xor(t, 2, 64));
      t = fmaxf(t, __shfl_xor(t, 4, 64));
      t = fmaxf(t, __shfl_xor(t, 8, 64));
      if (t > m_r[i] + 8.0f) {          // rescale only on real max growth
        float alpha = __expf(m_r[i] - t);
        m_r[i] = t;
        l_r[i] *= alpha;
#pragma unroll
        for (int ds = 0; ds < 4; ++ds) accO[ds][i] *= alpha;
      }
      float mm = m_r[i];
      float rs = 0.f;
#pragma unroll
      for (int s = 0; s < 4; ++s) {
        float p = __expf(sc[s][i] - mm);
        sc[s][i] = p;
        rs += p;
      }
      rs += __shfl_xor(rs, 1, 64);
      rs += __shfl_xor(rs, 2, 64);
      rs += __shfl_xor(rs, 4, 64);
      rs += __shfl_xor(rs, 8, 64);
      l_r[i] += rs;
    }

    // P: C layout -> wave-private LDS -> A fragments
#pragma unroll
    for (int i = 0; i < 4; ++i)
#pragma unroll
      for (int s = 0; s < 4; ++s)
        Pl[wave][lg * 4 + i][s * 16 + lr] = (bf16)sc[s][i];
    bf16x8 pa0 = *(const bf16x8*)&Pl[wave][lr][lg * 8];
    bf16x8 pa1 = *(const bf16x8*)&Pl[wave][lr][32 + lg * 8];

#pragma unroll
    for (int ds = 0; ds < 4; ++ds) {
      int row = ds * 16 + lr;
      const char* base = (const char*)Vs[cur] + row * 128;
      bf16x8 v0 = *(const bf16x8*)(base + ((lg * 16) ^ ((row & 7) << 4)));
      bf16x8 v1 = *(const bf16x8*)(base + ((64 + lg * 16) ^ ((row & 7) << 4)));
      accO[ds] = __builtin_amdgcn_mfma_f32_16x16x32_bf16(pa0, v0, accO[ds], 0, 0, 0);
      accO[ds] = __builtin_amdgcn_mfma_f32_16x16x32_bf16(pa1, v1, accO[ds], 0, 0, 0);
    }
    __builtin_amdgcn_s_barrier();   // all waves done reading cur
    cur ^= 1;
  }
#undef STAGE

  // epilogue: O / l -> bf16
#pragma unroll
  for (int i = 0; i < 4; ++i) {
    float inv = 1.0f / l_r[i];
    size_t orow = ((size_t)b * SEQ + qt0 + wave * 16 + lg * 4 + i) * DIM + h * HSZ;
#pragma unroll
    for (int ds = 0; ds < 4; ++ds)
      att[orow + ds * 16 + lr] = (bf16)(accO[ds][i] * inv);
  }
}

// ---------------------------------------------------------------- launcher
extern "C" void kernel_launch(void* const* d_in, const int* in_sizes, int n_in,
                              void* d_out, int out_size, void* d_ws, size_t ws_size,
                              hipStream_t stream) {
  const int*   idx    = (const int*)d_in[0];
  const float* tok    = (const float*)d_in[1];
  const float* pos    = (const float*)d_in[2];
  const float* ln1_g  = (const float*)d_in[3];
  const float* ln1_b  = (const float*)d_in[4];
  const float* wq     = (const float*)d_in[5];
  const float* wk     = (const float*)d_in[6];
  const float* wv     = (const float*)d_in[7];
  const float* wo     = (const float*)d_in[8];
  const float* bo     = (const float*)d_in[9];
  const float* ln2_g  = (const float*)d_in[10];
  const float* ln2_b  = (const float*)d_in[11];
  const float* w1     = (const float*)d_in[12];
  const float* b1     = (const float*)d_in[13];
  const float* w2     = (const float*)d_in[14];
  const float* b2     = (const float*)d_in[15];
  const float* lnf_g  = (const float*)d_in[16];
  const float* lnf_b  = (const float*)d_in[17];
  const float* head_w = (const float*)d_in[18];
  const float* head_b = (const float*)d_in[19];

  char* W = (char*)d_ws;
  float* x     = (float*)(W);                 // [4096][512] f32    8 MB
  bf16*  h     = (bf16*)(W + 8388608);        // [4096][512]        4 MB
  bf16*  qk    = (bf16*)(W + 12582912);       // [4096][1024]       8 MB
  bf16*  vTb   = (bf16*)(W + 20971520);       // [2][8][64][2048]   4 MB
  bf16*  attb  = (bf16*)(W + 25165824);       // [4096][512]        4 MB
  bf16*  ffn   = (bf16*)(W + 29360128);       // [4096][2048]      16 MB
  bf16*  wqkvT = (bf16*)(W + 46137344);       // 4L x [1536][512]   6 MB
  bf16*  woT   = (bf16*)(W + 52428800);       // 4L x [512][512]    2 MB
  bf16*  w1T   = (bf16*)(W + 54525952);       // 4L x [2048][512]   8 MB
  bf16*  w2T   = (bf16*)(W + 62914560);       // 4L x [512][2048]   8 MB
  bf16*  headT = (bf16*)(W + 71303168);       // [32000][512]      ~31.3 MB

  wt_all<<<12288 + 16000, 256, 0, stream>>>(wq, wk, wv, wo, w1, w2, head_w,
                                            wqkvT, woT, w1T, w2T, headT);
  embed_kernel<<<NTOK * DIM / 256, 256, 0, stream>>>(idx, tok, pos, x);

  dim3 gQKV(NTOK / 128, QS / 128);        // (32, 12)
  dim3 gD64(NTOK / 128, DIM / 64);        // (32, 8)  BN=64 -> 256 wg
  dim3 gF(NTOK / 128, 4 * DIM / 128);     // (32, 16)
  dim3 gV(NTOK / 128, VOC / 128);         // (32, 250)
  dim3 gA(SEQ / 64, NH, NB);              // (32, 8, 2)

  for (int l = 0; l < NL; ++l) {
    ln_kernel<<<NTOK, 256, 0, stream>>>(x, ln1_g + l * DIM, ln1_b + l * DIM, h);
    gemm128<128, false, false, true, true><<<gQKV, 256, 0, stream>>>(
        h, wqkvT + (size_t)l * QS * DIM, nullptr, nullptr, nullptr, qk, vTb,
        DIM, QS, QKS);
    fattn_kernel<<<gA, 256, 0, stream>>>(qk, vTb, attb);
    gemm128<64, false, true, false, false><<<gD64, 256, 0, stream>>>(
        attb, woT + (size_t)l * DIM * DIM, bo + l * DIM, x, x, nullptr, nullptr,
        DIM, DIM, DIM);
    ln_kernel<<<NTOK, 256, 0, stream>>>(x, ln2_g + l * DIM, ln2_b + l * DIM, h);
    gemm128<128, true, false, true, false><<<gF, 256, 0, stream>>>(
        h, w1T + (size_t)l * 4 * DIM * DIM, b1 + (size_t)l * 4 * DIM, nullptr,
        nullptr, ffn, nullptr, DIM, 4 * DIM, 4 * DIM);
    gemm128<64, false, true, false, false><<<gD64, 256, 0, stream>>>(
        ffn, w2T + (size_t)l * 4 * DIM * DIM, b2 + l * DIM, x, x, nullptr,
        nullptr, 4 * DIM, DIM, DIM);
  }

  ln_kernel<<<NTOK, 256, 0, stream>>>(x, lnf_g, lnf_b, h);
  gemm128<128, false, false, false, false><<<gV, 256, 0, stream>>>(
      h, headT, head_b, nullptr, (float*)d_out, nullptr, nullptr, DIM, VOC, VOC);
}